// Round 8
// baseline (330.266 us; speedup 1.0000x reference)
//
#include <hip/hip_runtime.h>
#include <cstdint>
#include <cstddef>

typedef unsigned short u16;
typedef short bf16x8 __attribute__((ext_vector_type(8)));
typedef short bf16x4 __attribute__((ext_vector_type(4)));
typedef float f32x4 __attribute__((ext_vector_type(4)));

constexpr int B_ = 4, T_ = 1024, E_ = 1024, H_ = 16, D_ = 64;

__device__ __forceinline__ float bf2f(u16 u) {
  union { unsigned u; float f; } v; v.u = ((unsigned)u) << 16; return v.f;
}
__device__ __forceinline__ u16 f2bf(float f) {
  union { float f; unsigned u; } v; v.f = f;
  return (u16)((v.u + 0x7fffu + ((v.u >> 16) & 1u)) >> 16);
}

#define GLD_LDS16(gp, lp)                                                      \
  __builtin_amdgcn_global_load_lds(                                            \
      (const __attribute__((address_space(1))) void*)(gp),                     \
      (__attribute__((address_space(3))) void*)(lp), 16, 0, 0)

#define SBAR()                                                                 \
  do {                                                                         \
    __builtin_amdgcn_sched_barrier(0);                                         \
    __builtin_amdgcn_s_barrier();                                              \
    __builtin_amdgcn_sched_barrier(0);                                         \
  } while (0)
#define WAIT_LGKM0()                                                           \
  do {                                                                         \
    asm volatile("s_waitcnt lgkmcnt(0)" ::: "memory");                         \
    __builtin_amdgcn_sched_barrier(0);                                         \
  } while (0)
#define WAIT_VM4()                                                             \
  do {                                                                         \
    asm volatile("s_waitcnt vmcnt(4)" ::: "memory");                           \
    __builtin_amdgcn_sched_barrier(0);                                         \
  } while (0)
#define WAIT_VM2()                                                             \
  do {                                                                         \
    asm volatile("s_waitcnt vmcnt(2)" ::: "memory");                           \
    __builtin_amdgcn_sched_barrier(0);                                         \
  } while (0)
#define WAIT_VM0()                                                             \
  do {                                                                         \
    asm volatile("s_waitcnt vmcnt(0)" ::: "memory");                           \
    __builtin_amdgcn_sched_barrier(0);                                         \
  } while (0)

// ---------------------------------------------------------------------------
// gemm_qkv8: 256x256-tile 8-wave deep-pipelined bf16 GEMM, C = A @ B^T.
// (round-2 win; ~96% of the K=1024 template ceiling — treated as done.)
// ---------------------------------------------------------------------------
__global__ __launch_bounds__(512, 2) void gemm_qkv8(
    const u16* __restrict__ A, const u16* __restrict__ Bm, u16* __restrict__ C)
{
  __shared__ u16 smem[65536];   // [buf(2)][half(4)][128*64] = 128 KiB

  const int tid  = threadIdx.x;
  const int lane = tid & 63;
  const int wave = tid >> 6;
  const int wm = wave >> 2;      // 0..1  (128-row block)
  const int wn = wave & 3;       // 0..3  (64-col block)
  const int fr = lane & 15;
  const int fg = lane >> 4;
  const int fx = fr & 7;
  const int m0 = blockIdx.y * 256;
  const int n0 = blockIdx.x * 256;

  auto stage = [&](int ktl, int half) {
    const int buf = ktl & 1;                 // logical buffer (pre-clamp!)
    int kt = (ktl > 15) ? 15 : ktl;          // tail: clamped src, benign dest
    const int k0 = kt << 6;
    const u16* src = (half < 2)
        ? (A  + (size_t)(m0 + (half & 1) * 128) * 1024)
        : (Bm + (size_t)(n0 + (half & 1) * 128) * 1024);
    u16* dst = smem + (buf << 15) + (half << 13);
    #pragma unroll
    for (int l = 0; l < 2; l++) {
      const int s = (l << 9) | tid;
      const int r = s >> 3, ch = s & 7;
      GLD_LDS16(src + (size_t)r * 1024 + k0 + ((ch ^ (r & 7)) << 3), dst + s * 8);
    }
  };

  f32x4 acc[8][4];
  #pragma unroll
  for (int i = 0; i < 8; i++)
    #pragma unroll
    for (int j = 0; j < 4; j++) acc[i][j] = f32x4{0.f, 0.f, 0.f, 0.f};

  // ---- prologue: tile0 all halves + tile1 {h2,h0}; wait tile0 landed ----
  stage(0, 0); stage(0, 1); stage(0, 2); stage(0, 3);
  stage(1, 2); stage(1, 0);
  WAIT_VM4();
  __builtin_amdgcn_s_barrier();
  __builtin_amdgcn_sched_barrier(0);

  const int ko0 = (fg ^ fx) << 3;          // ks=0 swizzled chunk offset (elems)
  const int ko1 = ((4 | fg) ^ fx) << 3;    // ks=1

  for (int t = 0; t < 16; t++) {
    const int buf = t & 1;
    const int ab = (buf << 15) + (wm << 13) + fr * 64;
    const int bb = (buf << 15) + 16384 + (wn << 12) + fr * 64;

    bf16x8 aF[4][2], bF[4][2];

    // -------- phase 0 : read aF(mt0-3) + bF(nt0-1); MFMA (lo, np0) --------
    #pragma unroll
    for (int mt = 0; mt < 4; mt++) {
      aF[mt][0] = *(const bf16x8*)(smem + ab + mt * 1024 + ko0);
      aF[mt][1] = *(const bf16x8*)(smem + ab + mt * 1024 + ko1);
    }
    #pragma unroll
    for (int nt = 0; nt < 2; nt++) {
      bF[nt][0] = *(const bf16x8*)(smem + bb + nt * 1024 + ko0);
      bF[nt][1] = *(const bf16x8*)(smem + bb + nt * 1024 + ko1);
    }
    stage(t + 1, 1);
    SBAR();
    WAIT_LGKM0();
    __builtin_amdgcn_s_setprio(1);
    #pragma unroll
    for (int mt = 0; mt < 4; mt++)
      #pragma unroll
      for (int nt = 0; nt < 2; nt++) {
        acc[mt][nt] = __builtin_amdgcn_mfma_f32_16x16x32_bf16(aF[mt][0], bF[nt][0], acc[mt][nt], 0, 0, 0);
        acc[mt][nt] = __builtin_amdgcn_mfma_f32_16x16x32_bf16(aF[mt][1], bF[nt][1], acc[mt][nt], 0, 0, 0);
      }
    __builtin_amdgcn_s_setprio(0);
    SBAR();

    // -------- phase 1 : read bF(nt2-3); MFMA (lo, np1) --------------------
    #pragma unroll
    for (int nt = 2; nt < 4; nt++) {
      bF[nt][0] = *(const bf16x8*)(smem + bb + nt * 1024 + ko0);
      bF[nt][1] = *(const bf16x8*)(smem + bb + nt * 1024 + ko1);
    }
    stage(t + 1, 3);
    SBAR();
    WAIT_LGKM0();
    __builtin_amdgcn_s_setprio(1);
    #pragma unroll
    for (int mt = 0; mt < 4; mt++)
      #pragma unroll
      for (int nt = 2; nt < 4; nt++) {
        acc[mt][nt] = __builtin_amdgcn_mfma_f32_16x16x32_bf16(aF[mt][0], bF[nt][0], acc[mt][nt], 0, 0, 0);
        acc[mt][nt] = __builtin_amdgcn_mfma_f32_16x16x32_bf16(aF[mt][1], bF[nt][1], acc[mt][nt], 0, 0, 0);
      }
    __builtin_amdgcn_s_setprio(0);
    SBAR();

    // -------- phase 2 : read aF(mt4-7, overwrite); MFMA (hi, np0) ---------
    #pragma unroll
    for (int mt = 0; mt < 4; mt++) {
      aF[mt][0] = *(const bf16x8*)(smem + ab + (4 + mt) * 1024 + ko0);
      aF[mt][1] = *(const bf16x8*)(smem + ab + (4 + mt) * 1024 + ko1);
    }
    stage(t + 2, 2);
    SBAR();
    WAIT_LGKM0();
    __builtin_amdgcn_s_setprio(1);
    #pragma unroll
    for (int mt = 0; mt < 4; mt++)
      #pragma unroll
      for (int nt = 0; nt < 2; nt++) {
        acc[4 + mt][nt] = __builtin_amdgcn_mfma_f32_16x16x32_bf16(aF[mt][0], bF[nt][0], acc[4 + mt][nt], 0, 0, 0);
        acc[4 + mt][nt] = __builtin_amdgcn_mfma_f32_16x16x32_bf16(aF[mt][1], bF[nt][1], acc[4 + mt][nt], 0, 0, 0);
      }
    __builtin_amdgcn_s_setprio(0);
    SBAR();

    // -------- phase 3 : MFMA (hi, np1); boundary vmcnt(4) -----------------
    stage(t + 2, 0);
    SBAR();
    __builtin_amdgcn_s_setprio(1);
    #pragma unroll
    for (int mt = 0; mt < 4; mt++)
      #pragma unroll
      for (int nt = 2; nt < 4; nt++) {
        acc[4 + mt][nt] = __builtin_amdgcn_mfma_f32_16x16x32_bf16(aF[mt][0], bF[nt][0], acc[4 + mt][nt], 0, 0, 0);
        acc[4 + mt][nt] = __builtin_amdgcn_mfma_f32_16x16x32_bf16(aF[mt][1], bF[nt][1], acc[4 + mt][nt], 0, 0, 0);
      }
    __builtin_amdgcn_s_setprio(0);
    WAIT_VM4();                             // tile t+1 fully in LDS
    __builtin_amdgcn_s_barrier();
    __builtin_amdgcn_sched_barrier(0);
  }

  // ---- epilogue ----
  u16* Cp = C + (size_t)(m0 + wm * 128) * 4096 + n0 + wn * 64;
  #pragma unroll
  for (int mt = 0; mt < 8; mt++)
    #pragma unroll
    for (int nt = 0; nt < 4; nt++)
      #pragma unroll
      for (int r2 = 0; r2 < 4; r2++)
        Cp[(size_t)(mt * 16 + fg * 4 + r2) * 4096 + nt * 16 + fr] = f2bf(acc[mt][nt][r2]);
}

// ---------------------------------------------------------------------------
// gemm_bt8: batched 128x128-tile 8-wave deep-pipelined bf16 GEMM (round-6 win)
// ---------------------------------------------------------------------------
template<bool CBF16>
__global__ __launch_bounds__(512, 2) void gemm_bt8(
    const u16* __restrict__ A, const u16* __restrict__ Bm, void* __restrict__ Cv,
    int K, int lda, int ldb, int ldc,
    long batchA, long batchB, long batchC, float alpha)
{
  __shared__ u16 smem[32768];   // [buf2][unit2][128*64] = 64 KiB

  const int tid  = threadIdx.x;
  const int lane = tid & 63;
  const int wave = tid >> 6;
  const int wm = wave >> 2;      // 0..1  (64-row block)
  const int wn = wave & 3;       // 0..3  (32-col block)
  const int fr = lane & 15;
  const int fg = lane >> 4;
  const int fx = fr & 7;
  const int m0 = blockIdx.y * 128;
  const int n0 = blockIdx.x * 128;
  const int z  = blockIdx.z;
  const u16* Ab = A  + (size_t)z * batchA;
  const u16* Bb = Bm + (size_t)z * batchB;
  const int NTK = K >> 6;

  auto stage = [&](int ktl, int unit) {
    const int buf = ktl & 1;                 // logical buffer (pre-clamp!)
    int kt = (ktl > NTK - 1) ? NTK - 1 : ktl;
    const int k0 = kt << 6;
    const u16* src = unit ? (Bb + (size_t)n0 * ldb) : (Ab + (size_t)m0 * lda);
    const int ld = unit ? ldb : lda;
    u16* dst = smem + (buf << 14) + (unit << 13);
    #pragma unroll
    for (int l = 0; l < 2; l++) {
      const int s = (l << 9) | tid;
      const int r = s >> 3, ch = s & 7;
      GLD_LDS16(src + (size_t)r * ld + k0 + ((ch ^ (r & 7)) << 3), dst + s * 8);
    }
  };

  f32x4 acc[4][2];
  #pragma unroll
  for (int i = 0; i < 4; i++)
    #pragma unroll
    for (int j = 0; j < 2; j++) acc[i][j] = f32x4{0.f, 0.f, 0.f, 0.f};

  // ---- prologue: tile0 {A,B} + tile1 {A}; wait tile0 landed ----
  stage(0, 0); stage(0, 1); stage(1, 0);
  WAIT_VM2();
  __builtin_amdgcn_s_barrier();
  __builtin_amdgcn_sched_barrier(0);

  const int ko0 = (fg ^ fx) << 3;
  const int ko1 = ((4 | fg) ^ fx) << 3;

  for (int t = 0; t < NTK; t++) {
    const int buf = t & 1;
    const int ab = (buf << 14) + (wm * 64 + fr) * 64;
    const int bb = (buf << 14) + 8192 + (wn * 32 + fr) * 64;

    bf16x8 aF[4][2], bF[2];

    // -------- phase 0 : read all aF + bF(nt0); stage (t+1,B) --------------
    #pragma unroll
    for (int mt = 0; mt < 4; mt++) {
      aF[mt][0] = *(const bf16x8*)(smem + ab + mt * 1024 + ko0);
      aF[mt][1] = *(const bf16x8*)(smem + ab + mt * 1024 + ko1);
    }
    bF[0] = *(const bf16x8*)(smem + bb + ko0);
    bF[1] = *(const bf16x8*)(smem + bb + ko1);
    stage(t + 1, 1);
    SBAR();
    WAIT_LGKM0();
    __builtin_amdgcn_s_setprio(1);
    #pragma unroll
    for (int mt = 0; mt < 4; mt++) {
      acc[mt][0] = __builtin_amdgcn_mfma_f32_16x16x32_bf16(aF[mt][0], bF[0], acc[mt][0], 0, 0, 0);
      acc[mt][0] = __builtin_amdgcn_mfma_f32_16x16x32_bf16(aF[mt][1], bF[1], acc[mt][0], 0, 0, 0);
    }
    __builtin_amdgcn_s_setprio(0);
    SBAR();

    // -------- phase 1 : read bF(nt1); stage (t+2,A); boundary vmcnt(2) ----
    bF[0] = *(const bf16x8*)(smem + bb + 1024 + ko0);
    bF[1] = *(const bf16x8*)(smem + bb + 1024 + ko1);
    stage(t + 2, 0);
    SBAR();
    WAIT_LGKM0();
    __builtin_amdgcn_s_setprio(1);
    #pragma unroll
    for (int mt = 0; mt < 4; mt++) {
      acc[mt][1] = __builtin_amdgcn_mfma_f32_16x16x32_bf16(aF[mt][0], bF[0], acc[mt][1], 0, 0, 0);
      acc[mt][1] = __builtin_amdgcn_mfma_f32_16x16x32_bf16(aF[mt][1], bF[1], acc[mt][1], 0, 0, 0);
    }
    __builtin_amdgcn_s_setprio(0);
    WAIT_VM2();                             // tile t+1 fully in LDS
    __builtin_amdgcn_s_barrier();
    __builtin_amdgcn_sched_barrier(0);
  }

  // ---- epilogue (drain tail stages; then store) ----
  WAIT_VM0();
  #pragma unroll
  for (int mt = 0; mt < 4; mt++) {
    #pragma unroll
    for (int nt = 0; nt < 2; nt++) {
      const int row = m0 + wm * 64 + mt * 16 + fg * 4;
      const int col = n0 + wn * 32 + nt * 16 + fr;
      #pragma unroll
      for (int r2 = 0; r2 < 4; r2++) {
        const float vv = acc[mt][nt][r2] * alpha;
        const size_t ci = (size_t)z * batchC + (size_t)(row + r2) * ldc + col;
        if constexpr (CBF16) ((u16*)Cv)[ci] = f2bf(vv);
        else                 ((float*)Cv)[ci] = vv;
      }
    }
  }
}

// ---------------------------------------------------------------------------
// gemm_echo8: split-bf16 GEMM, 2-phase deep pipeline (round-7 win).
// ---------------------------------------------------------------------------
__global__ __launch_bounds__(512, 2) void gemm_echo8(
    const u16* __restrict__ A, const u16* __restrict__ Alo,
    const u16* __restrict__ Bm, const u16* __restrict__ Blo,
    u16* __restrict__ echoT, float* __restrict__ sc)
{
  __shared__ u16 smem[65536];   // [buf2][unit4][128*64] = 128 KiB

  const int tid  = threadIdx.x;
  const int lane = tid & 63;
  const int wave = tid >> 6;
  const int wm = wave >> 2;      // 0..1  (64-row block)
  const int wn = wave & 3;       // 0..3  (32-col block)
  const int fr = lane & 15;
  const int fg = lane >> 4;
  const int fx = fr & 7;
  const int m0 = blockIdx.y * 128;
  const int n0 = blockIdx.x * 128;

  auto stage = [&](int ktl, int unit) {
    const int buf = ktl & 1;                 // logical buffer (pre-clamp!)
    int kt = (ktl > 15) ? 15 : ktl;          // tail: clamped src, benign dest
    const int k0 = kt << 6;
    const u16* src = (unit == 0) ? A   + (size_t)m0 * 1024
                   : (unit == 1) ? Alo + (size_t)m0 * 1024
                   : (unit == 2) ? Bm  + (size_t)n0 * 1024
                   :               Blo + (size_t)n0 * 1024;
    u16* dst = smem + (buf << 15) + (unit << 13);
    #pragma unroll
    for (int l = 0; l < 2; l++) {
      const int s = (l << 9) | tid;
      const int r = s >> 3, ch = s & 7;
      GLD_LDS16(src + (size_t)r * 1024 + k0 + ((ch ^ (r & 7)) << 3), dst + s * 8);
    }
  };

  f32x4 acc[4][2];
  #pragma unroll
  for (int i = 0; i < 4; i++)
    #pragma unroll
    for (int j = 0; j < 2; j++) acc[i][j] = f32x4{0.f, 0.f, 0.f, 0.f};

  // ---- prologue: tile0 all units + tile1 {Ahi,Alo}; wait tile0 landed ----
  stage(0, 0); stage(0, 1); stage(0, 2); stage(0, 3);
  stage(1, 0); stage(1, 1);
  WAIT_VM4();
  __builtin_amdgcn_s_barrier();
  __builtin_amdgcn_sched_barrier(0);

  const int ko0 = (fg ^ fx) << 3;          // ks=0 swizzled chunk offset (elems)
  const int ko1 = ((4 | fg) ^ fx) << 3;    // ks=1

  for (int t = 0; t < 16; t++) {
    const int buf = t & 1;
    const int ab = (buf << 15) + (wm * 64 + fr) * 64;
    const int bb = (buf << 15) + 16384 + (wn * 32 + fr) * 64;

    bf16x8 aH[4][2], aL[4][2], bH[2], bL[2];

    // -------- phase 0' : read all a-frags + b(nt0, ks0+ks1); MFMA nt0 -----
    #pragma unroll
    for (int mt = 0; mt < 4; mt++) {
      aH[mt][0] = *(const bf16x8*)(smem + ab + mt * 1024 + ko0);
      aH[mt][1] = *(const bf16x8*)(smem + ab + mt * 1024 + ko1);
      aL[mt][0] = *(const bf16x8*)(smem + ab + 8192 + mt * 1024 + ko0);
      aL[mt][1] = *(const bf16x8*)(smem + ab + 8192 + mt * 1024 + ko1);
    }
    bH[0] = *(const bf16x8*)(smem + bb + ko0);
    bL[0] = *(const bf16x8*)(smem + bb + 8192 + ko0);
    bH[1] = *(const bf16x8*)(smem + bb + ko1);
    bL[1] = *(const bf16x8*)(smem + bb + 8192 + ko1);
    stage(t + 1, 2);
    stage(t + 1, 3);
    SBAR();
    WAIT_LGKM0();
    __builtin_amdgcn_s_setprio(1);
    #pragma unroll
    for (int mt = 0; mt < 4; mt++) {
      acc[mt][0] = __builtin_amdgcn_mfma_f32_16x16x32_bf16(aH[mt][0], bH[0], acc[mt][0], 0, 0, 0);
      acc[mt][0] = __builtin_amdgcn_mfma_f32_16x16x32_bf16(aL[mt][0], bH[0], acc[mt][0], 0, 0, 0);
      acc[mt][0] = __builtin_amdgcn_mfma_f32_16x16x32_bf16(aH[mt][0], bL[0], acc[mt][0], 0, 0, 0);
    }
    #pragma unroll
    for (int mt = 0; mt < 4; mt++) {
      acc[mt][0] = __builtin_amdgcn_mfma_f32_16x16x32_bf16(aH[mt][1], bH[1], acc[mt][0], 0, 0, 0);
      acc[mt][0] = __builtin_amdgcn_mfma_f32_16x16x32_bf16(aL[mt][1], bH[1], acc[mt][0], 0, 0, 0);
      acc[mt][0] = __builtin_amdgcn_mfma_f32_16x16x32_bf16(aH[mt][1], bL[1], acc[mt][0], 0, 0, 0);
    }
    __builtin_amdgcn_s_setprio(0);
    SBAR();

    // -------- phase 1' : read b(nt1, ks0+ks1); MFMA nt1; boundary ---------
    bH[0] = *(const bf16x8*)(smem + bb + 1024 + ko0);
    bL[0] = *(const bf16x8*)(smem + bb + 8192 + 1024 + ko0);
    bH[1] = *(const bf16x8*)(smem + bb + 1024 + ko1);
    bL[1] = *(const bf16x8*)(smem + bb + 8192 + 1024 + ko1);
    stage(t + 2, 0);
    stage(t + 2, 1);
    SBAR();
    WAIT_LGKM0();
    __builtin_amdgcn_s_setprio(1);
    #pragma unroll
    for (int mt = 0; mt < 4; mt++) {
      acc[mt][1] = __builtin_amdgcn_mfma_f32_16x16x32_bf16(aH[mt][0], bH[0], acc[mt][1], 0, 0, 0);
      acc[mt][1] = __builtin_amdgcn_mfma_f32_16x16x32_bf16(aL[mt][0], bH[0], acc[mt][1], 0, 0, 0);
      acc[mt][1] = __builtin_amdgcn_mfma_f32_16x16x32_bf16(aH[mt][0], bL[0], acc[mt][1], 0, 0, 0);
    }
    #pragma unroll
    for (int mt = 0; mt < 4; mt++) {
      acc[mt][1] = __builtin_amdgcn_mfma_f32_16x16x32_bf16(aH[mt][1], bH[1], acc[mt][1], 0, 0, 0);
      acc[mt][1] = __builtin_amdgcn_mfma_f32_16x16x32_bf16(aL[mt][1], bH[1], acc[mt][1], 0, 0, 0);
      acc[mt][1] = __builtin_amdgcn_mfma_f32_16x16x32_bf16(aH[mt][1], bL[1], acc[mt][1], 0, 0, 0);
    }
    __builtin_amdgcn_s_setprio(0);
    WAIT_VM4();                             // tile t+1 fully in LDS
    __builtin_amdgcn_s_barrier();
    __builtin_amdgcn_sched_barrier(0);
  }

  // ---- fused epilogue (drain tail stages before reusing smem) ----
  asm volatile("s_waitcnt vmcnt(0) lgkmcnt(0)" ::: "memory");
  __builtin_amdgcn_sched_barrier(0);
  __builtin_amdgcn_s_barrier();
  __builtin_amdgcn_sched_barrier(0);

  const int b   = m0 >> 10;
  const int t0l = m0 & 1023;
  u16* lt = smem;                  // [f(128)][t(128)] tile, pad 132

  #pragma unroll
  for (int mt = 0; mt < 4; mt++) {
    float sq[4] = {0.f, 0.f, 0.f, 0.f};
    #pragma unroll
    for (int nt = 0; nt < 2; nt++) {
      const int cl = wn * 32 + nt * 16 + fr;
      #pragma unroll
      for (int r2 = 0; r2 < 4; r2++) {
        const float vv = acc[mt][nt][r2];
        sq[r2] += vv * vv;
        lt[cl * 132 + wm * 64 + mt * 16 + fg * 4 + r2] = f2bf(vv);
      }
    }
    #pragma unroll
    for (int m2 = 1; m2 < 16; m2 <<= 1) {
      sq[0] += __shfl_xor(sq[0], m2, 64);
      sq[1] += __shfl_xor(sq[1], m2, 64);
      sq[2] += __shfl_xor(sq[2], m2, 64);
      sq[3] += __shfl_xor(sq[3], m2, 64);
    }
    if (fr == 0) {
      #pragma unroll
      for (int r2 = 0; r2 < 4; r2++)
        atomicAdd(&sc[(size_t)b * T_ + t0l + wm * 64 + mt * 16 + fg * 4 + r2], sq[r2]);
    }
  }
  __syncthreads();
  for (int s = tid; s < 128 * 128; s += 512) {
    const int f = s >> 7, tt = s & 127;
    echoT[((size_t)b * E_ + n0 + f) * T_ + t0l + tt] = lt[f * 132 + tt];
  }
}

// ---------------------------------------------------------------------------
// flash1p2: flash-fused branch 1 + gated combine.  Round-8: the combine
// epilogue is LDS-staged and vectorized — o1 fragments go into the dead
// sK[bfree] buffer (last-used K buffer; next phase uses bfree^1), then a
// cooperative loop does bf16x8 loads of o1/out2/out3 and a 16B comb store.
// Round-7's per-lane scalar u16 reads of out2/out3 at fragment addresses
// caused ~2.6x overfetch (FETCH 41->83 MB) and +20 µs.  Arithmetic and
// rounding identical -> bit-exact.
// ---------------------------------------------------------------------------
__global__ __launch_bounds__(256, 4) void flash1p2(
    const u16* __restrict__ qkvr, const u16* __restrict__ vTb,
    const u16* __restrict__ out2, const u16* __restrict__ out3,
    const float* __restrict__ gate, u16* __restrict__ comb) {
  const int x = blockIdx.x, h = blockIdx.y, b = blockIdx.z;
  const int tid = threadIdx.x, lane = tid & 63, w = tid >> 6;
  const int fr = lane & 15, fg = lane >> 4;
  const int itA = x, itB = 15 - x;     // q-tiles of 64 rows

  __shared__ u16 sQ[4096];             // 64 x 64
  __shared__ u16 sK[2][8192];          // 128 x 64, double-buffered
  __shared__ u16 sV[2][8192];

  const u16* Kb = qkvr + (size_t)(b * T_) * 4096 + 1024 + h * 64;
  const u16* Vb = vTb + (size_t)(b * H_ + h) * (D_ * T_);

  // gate coefficients (exactly as combine_gate computed them)
  const float g0 = gate[h * 3 + 0], g1 = gate[h * 3 + 1], g2 = gate[h * 3 + 2];
  const float gmx = fmaxf(g0, fmaxf(g1, g2));
  const float e0 = __expf(g0 - gmx), e1 = __expf(g1 - gmx), e2 = __expf(g2 - gmx);
  const float ginv = 1.0f / (e0 + e1 + e2);

  auto stageQ = [&](int it) {
    const u16* Qb = qkvr + ((size_t)(b * T_) + it * 64) * 4096 + h * 64;
    #pragma unroll
    for (int s0 = 0; s0 < 512; s0 += 256) {
      const int s = s0 + tid;
      const int l = s & 63, g = s >> 6;
      const int row = (g >> 1) * 16 + (l & 15);
      const int c8  = (g & 1) * 4 + (l >> 4);
      GLD_LDS16(Qb + (size_t)row * 4096 + c8 * 8, &sQ[s * 8]);
    }
  };
  auto stageKV = [&](int jt, int bi) {
    #pragma unroll
    for (int s0 = 0; s0 < 1024; s0 += 256) {
      const int s = s0 + tid;
      const int l = s & 63, g = s >> 6;
      const int row = (g >> 1) * 16 + (l & 15);
      const int c8  = (g & 1) * 4 + (l >> 4);
      GLD_LDS16(Kb + (size_t)(jt * 128 + row) * 4096 + c8 * 8, &sK[bi][s * 8]);
    }
    #pragma unroll
    for (int s0 = 0; s0 < 1024; s0 += 256) {
      const int s = s0 + tid;
      const int jc = s >> 6, d = s & 63;
      GLD_LDS16(Vb + ((size_t)(jt * 16 + jc)) * 512 + d * 8, &sV[bi][s * 8]);
    }
  };

  // ---- prologue: Q(itA) + K/V(0) -> buf0 ----
  stageQ(itA);
  stageKV(0, 0);
  asm volatile("s_waitcnt vmcnt(0)" ::: "memory");
  __syncthreads();

  bf16x8 bQ[2];
  f32x4 accO[4];
  float mrow, lrow;
  int cnt = 0;                          // global step counter -> buffer parity

  #pragma unroll 1
  for (int ph = 0; ph < 2; ph++) {
    const int it = ph ? itB : itA;
    const int nsteps = (it >> 1) + 1;

    #pragma unroll
    for (int kk = 0; kk < 2; kk++)
      bQ[kk] = *(const bf16x8*)&sQ[(((w * 2 + kk) << 6) | lane) * 8];
    mrow = -3.0e38f; lrow = 0.f;
    #pragma unroll
    for (int nd = 0; nd < 4; nd++) accO[nd] = f32x4{0.f, 0.f, 0.f, 0.f};

    for (int jt = 0; jt < nsteps; jt++, cnt++) {
      const int bi = cnt & 1;

      // ---- issue next-step staging early (lands during compute) ----
      if (jt < nsteps - 1) {
        stageKV(jt + 1, bi ^ 1);
      } else if (ph == 0) {
        stageQ(itB);
        stageKV(0, bi ^ 1);
      }

      // ---- QK^T (swapped operands: C rows = keys, cols = queries) ----
      f32x4 accST[8];
      #pragma unroll
      for (int nf = 0; nf < 8; nf++) accST[nf] = f32x4{0.f, 0.f, 0.f, 0.f};
      #pragma unroll
      for (int kk = 0; kk < 2; kk++) {
        #pragma unroll
        for (int nf = 0; nf < 8; nf++) {
          const bf16x8 aK = *(const bf16x8*)&sK[bi][((((nf << 1) | kk) << 6) | lane) * 8];
          accST[nf] = __builtin_amdgcn_mfma_f32_16x16x32_bf16(aK, bQ[kk], accST[nf], 0, 0, 0);
        }
      }

      // ---- online softmax (per-wave 16 q-rows) ----
      const bool diag = (jt == nsteps - 1);
      const int iloc = it * 64 + w * 16 + fr;          // global q index
      float sv[8][4];
      float rmax = -3.0e38f;
      #pragma unroll
      for (int nf = 0; nf < 8; nf++)
        #pragma unroll
        for (int r = 0; r < 4; r++) {
          float s = accST[nf][r] * 0.125f;
          if (diag && (jt * 128 + nf * 16 + fg * 4 + r) > iloc) s = -3.0e38f;
          sv[nf][r] = s;
          rmax = fmaxf(rmax, s);
        }
      rmax = fmaxf(rmax, __shfl_xor(rmax, 16, 64));
      rmax = fmaxf(rmax, __shfl_xor(rmax, 32, 64));
      const float mn = fmaxf(mrow, rmax);
      const float al = __expf(mrow - mn);
      mrow = mn;
      float ps = 0.f;
      bf16x4 pf[8];
      #pragma unroll
      for (int nf = 0; nf < 8; nf++)
        #pragma unroll
        for (int r = 0; r < 4; r++) {
          const float pv = __expf(sv[nf][r] - mn);
          ps += pv;
          pf[nf][r] = (short)f2bf(pv);
        }
      ps += __shfl_xor(ps, 16, 64);
      ps += __shfl_xor(ps, 32, 64);
      lrow = lrow * al + ps;
      #pragma unroll
      for (int r = 0; r < 4; r++) {
        const float alr = __shfl(al, fg * 4 + r, 64);
        #pragma unroll
        for (int nd = 0; nd < 4; nd++) accO[nd][r] *= alr;
      }

      // ---- PV ----
      #pragma unroll
      for (int kc = 0; kc < 8; kc++) {
        bf16x8 bV[4];
        #pragma unroll
        for (int nd = 0; nd < 4; nd++) {
          const bf16x4 vv = *(const bf16x4*)&sV[bi][
              (((kc * 2 + (fg >> 1)) * 64 + nd * 16 + fr) * 8) + (fg & 1) * 4];
          bV[nd] = bf16x8{vv[0], vv[1], vv[2], vv[3], 0, 0, 0, 0};
        }
        const bf16x4 pp = pf[kc];
        const bf16x8 pA = bf16x8{pp[0], pp[1], pp[2], pp[3], 0, 0, 0, 0};
        #pragma unroll
        for (int nd = 0; nd < 4; nd++)
          accO[nd] = __builtin_amdgcn_mfma_f32_16x16x32_bf16(pA, bV[nd], accO[nd], 0, 0, 0);
      }

      // ---- late wait: prefetch landed + everyone done with buffers ----
      asm volatile("s_waitcnt vmcnt(0)" ::: "memory");
      __syncthreads();
    }

    // ---- epilogue: LDS-staged vectorized gated combine ----
    // sK[bfree] (last-used K buffer) is dead: next phase uses bfree^1, and
    // the ph1 prefetch already landed in bfree^1 before the final barrier.
    const int bfree = (cnt + 1) & 1;       // == (cnt-1)&1, last step's bi
    u16* lt = &sK[bfree][0];               // [64][72] o1 tile (9216 B)
    const float li = 1.0f / lrow;
    #pragma unroll
    for (int r = 0; r < 4; r++) {
      const float linv = __shfl(li, fg * 4 + r, 64);
      const int row = w * 16 + fg * 4 + r;
      #pragma unroll
      for (int nd = 0; nd < 4; nd++)
        lt[row * 72 + nd * 16 + fr] = f2bf(accO[nd][r] * linv);
    }
    __syncthreads();
    const size_t rbase = ((size_t)(b * T_) + it * 64) * E_ + h * 64;
    #pragma unroll
    for (int s0 = 0; s0 < 512; s0 += 256) {
      const int s = s0 + tid;
      const int row = s >> 3, c8 = (s & 7) * 8;
      const size_t gidx = rbase + (size_t)row * E_ + c8;
      const bf16x8 o1v = *(const bf16x8*)&lt[row * 72 + c8];
      const bf16x8 o2v = *(const bf16x8*)&out2[gidx];
      const bf16x8 o3v = *(const bf16x8*)&out3[gidx];
      bf16x8 ov;
      #pragma unroll
      for (int e = 0; e < 8; e++) {
        const float o = (e0 * bf2f((u16)o1v[e]) + e1 * bf2f((u16)o2v[e])
                       + e2 * bf2f((u16)o3v[e])) * ginv;
        ov[e] = (short)f2bf(o);
      }
      *(bf16x8*)&comb[gidx] = ov;
    }
    __syncthreads();   // fence lt reads against next phase's prefetch into sK[bfree]
  }
}

// ---------------------------------------------------------------------------
// Reductions
// ---------------------------------------------------------------------------
__device__ __forceinline__ float block_max256(float v, float* red) {
  #pragma unroll
  for (int m = 32; m > 0; m >>= 1) v = fmaxf(v, __shfl_xor(v, m, 64));
  if ((threadIdx.x & 63) == 0) red[threadIdx.x >> 6] = v;
  __syncthreads();
  const float r = fmaxf(fmaxf(red[0], red[1]), fmaxf(red[2], red[3]));
  __syncthreads();
  return r;
}
__device__ __forceinline__ float block_sum256(float v, float* red) {
  #pragma unroll
  for (int m = 32; m > 0; m >>= 1) v += __shfl_xor(v, m, 64);
  if ((threadIdx.x & 63) == 0) red[threadIdx.x >> 6] = v;
  __syncthreads();
  const float r = (red[0] + red[1]) + (red[2] + red[3]);
  __syncthreads();
  return r;
}

// ---------------------------------------------------------------------------
// cast_all: x split (4096 blocks) | wq/wk/wv/wvr -> wcat (4096) |
//           wo -> wob (1024) | wj split (1024).  One dispatch, 10240 blocks.
// ---------------------------------------------------------------------------
__global__ __launch_bounds__(256) void cast_all(
    const float* __restrict__ x, const float* __restrict__ wq,
    const float* __restrict__ wk, const float* __restrict__ wv,
    const float* __restrict__ wvr, const float* __restrict__ wo,
    const float* __restrict__ wj,
    u16* __restrict__ xb, u16* __restrict__ xlo, u16* __restrict__ wcat,
    u16* __restrict__ wob, u16* __restrict__ wjb, u16* __restrict__ wjlo) {
  const int bid = blockIdx.x;
  if (bid < 4096) {
    const size_t i = ((size_t)bid * 256 + threadIdx.x) * 4;
    const float4 v = *(const float4*)(x + i);
    ushort4 oh, ol;
    oh.x = f2bf(v.x); ol.x = f2bf(v.x - bf2f(oh.x));
    oh.y = f2bf(v.y); ol.y = f2bf(v.y - bf2f(oh.y));
    oh.z = f2bf(v.z); ol.z = f2bf(v.z - bf2f(oh.z));
    oh.w = f2bf(v.w); ol.w = f2bf(v.w - bf2f(oh.w));
    *(ushort4*)(xb + i) = oh;
    *(ushort4*)(xlo + i) = ol;
  } else if (bid < 8192) {
    const int r = (bid - 4096) >> 10;
    const float* src = (r == 0) ? wq : (r == 1) ? wk : (r == 2) ? wv : wvr;
    const size_t i = ((size_t)((bid - 4096) & 1023) * 256 + threadIdx.x) * 4;
    const float4 v = *(const float4*)(src + i);
    ushort4 o;
    o.x = f2bf(v.x); o.y = f2bf(v.y); o.z = f2bf(v.z); o.w = f2bf(v.w);
    *(ushort4*)(wcat + (size_t)r * (1 << 20) + i) = o;
  } else if (bid < 9216) {
    const size_t i = ((size_t)(bid - 8192) * 256 + threadIdx.x) * 4;
    const float4 v = *(const float4*)(wo + i);
    ushort4 o;
    o.x = f2bf(v.x); o.y = f2bf(v.y); o.z = f2bf(v.z); o.w = f2bf(v.w);
    *(ushort4*)(wob + i) = o;
  } else {
    const size_t i = ((size_t)(bid - 9216) * 256 + threadIdx.x) * 4;
    const float4 v = *(const float4*)(wj + i);
    ushort4 oh, ol;
    oh.x = f2bf(v.x); ol.x = f2bf(v.x - bf2f(oh.x));
    oh.y = f2bf(v.y); ol.y = f2bf(v.y - bf2f(oh.y));
    oh.z = f2bf(v.z); ol.z = f2bf(v.z - bf2f(oh.z));
    oh.w = f2bf(v.w); ol.w = f2bf(v.w - bf2f(oh.w));
    *(ushort4*)(wjb + i) = oh;
    *(ushort4*)(wjlo + i) = ol;
  }
}

// ---------------------------------------------------------------------------
// s2_direct: s2[b,h,t] = dot(x[b,t,:], wr[h,:,t]) / 8 without materializing
// wrT. Grid (T/32, H).
// ---------------------------------------------------------------------------
__global__ __launch_bounds__(256) void s2_direct(
    const u16* __restrict__ xb, const float* __restrict__ wr, float* __restrict__ s2) {
  const int t0 = blockIdx.x * 32, h = blockIdx.y;
  const int tt = threadIdx.x & 31, eg = threadIdx.x >> 5;
  float acc[4] = {0.f, 0.f, 0.f, 0.f};
  const float* wp = wr + (size_t)h * E_ * T_ + t0 + tt;
  for (int ec = 0; ec < 8; ec++) {
    const int e0 = ec * 128 + eg * 16;
    bf16x8 xv[4][2];
    #pragma unroll
    for (int b = 0; b < 4; b++) {
      const u16* xp = xb + ((size_t)(b * T_) + t0 + tt) * E_ + e0;
      xv[b][0] = *(const bf16x8*)xp;
      xv[b][1] = *(const bf16x8*)(xp + 8);
    }
    #pragma unroll
    for (int e2 = 0; e2 < 16; e2++) {
      const float w = wp[(size_t)(e0 + e2) * T_];
      #pragma unroll
      for (int b = 0; b < 4; b++)
        acc[b] += bf2f((u16)xv[b][e2 >> 3][e2 & 7]) * w;
    }
  }
  __shared__ float red[8][4][33];
  #pragma unroll
  for (int b = 0; b < 4; b++) red[eg][b][tt] = acc[b];
  __syncthreads();
  if (threadIdx.x < 128) {
    const int b = threadIdx.x >> 5, t = threadIdx.x & 31;
    float s = 0.f;
    #pragma unroll
    for (int g = 0; g < 8; g++) s += red[g][b][t];
    s2[((size_t)b * H_ + h) * T_ + t0 + t] = s * 0.125f;
  }
}

// ---------------------------------------------------------------------------
// a3[b,i,j] = softmax_{j<=i}(sc_i*sc_j/1024)  (sc holds raw sum of squares)
// ---------------------------------------------------------------------------
__global__ __launch_bounds__(256) void a3_softmax(const float* __restrict__ sc, u16* __restrict__ a3) {
  const int i = blockIdx.x;
  const int b = blockIdx.y;
  const float* sr = sc + (size_t)b * T_;
  const float sci = sr[i] * 0.03125f;
  u16* row = a3 + ((size_t)b * T_ + i) * T_;
  __shared__ float red[4];
  float v[4];
  float m = -3.0e38f;
  #pragma unroll
  for (int k = 0; k < 4; k++) {
    const int j = threadIdx.x + k * 256;
    const float xv = (j <= i) ? sci * (sr[j] * 0.03125f) : -3.0e38f;
    v[k] = xv;
    m = fmaxf(m, xv);
  }
  m = block_max256(m, red);
  float s = 0.f;
  #pragma unroll
  for (int k = 0; k < 4; k++) {
    const int j = threadIdx.x + k * 256;
    const float p = (j <= i) ? __expf(v[k] - m) : 0.f;
    v[k] = p;
    s += p;
  }
  s = block_sum256(s, red);
  const float inv = 1.0f / s;
  #pragma unroll
  for (int k = 0; k < 4; k++) {
    const int j = threadIdx.x + k * 256;
    row[j] = f2bf(v[k] * inv);
  }
}

// ---------------------------------------------------------------------------
// Branch 2: prefix scan (round-1 win). rv strided view into qkvr.
// ---------------------------------------------------------------------------
__global__ __launch_bounds__(1024) void branch2_scan(
    const float* __restrict__ s2, const u16* __restrict__ rv, int ldrv,
    u16* __restrict__ out2) {
  const int h = blockIdx.x, b = blockIdx.y;
  const int tid = threadIdx.x;
  const int lane = tid & 63;
  const int wv = tid >> 6;

  const float* srow = s2 + ((size_t)b * H_ + h) * T_;

  __shared__ float wbuf[T_];
  __shared__ float numtot[16][64];
  __shared__ float dentot[16];
  __shared__ float redm[16];

  float m = srow[tid];
  #pragma unroll
  for (int mk = 32; mk > 0; mk >>= 1) m = fmaxf(m, __shfl_xor(m, mk, 64));
  if (lane == 0) redm[wv] = m;
  __syncthreads();
  m = redm[0];
  #pragma unroll
  for (int i2 = 1; i2 < 16; i2++) m = fmaxf(m, redm[i2]);

  wbuf[tid] = __expf(srow[tid] - m);
  __syncthreads();

  const u16* rvp = rv + (size_t)(b * T_) * ldrv + h * D_ + lane;
  const int j0 = wv * 64;
  float num = 0.f, den = 0.f;
  #pragma unroll 8
  for (int j2 = 0; j2 < 64; j2++) {
    const float w = wbuf[j0 + j2];
    den += w;
    num += w * bf2f(rvp[(size_t)(j0 + j2) * ldrv]);
  }
  numtot[wv][lane] = num;
  if (lane == 0) dentot[wv] = den;
  __syncthreads();

  float num_off = 0.f, den_off = 0.f;
  for (int w2 = 0; w2 < wv; w2++) {
    num_off += numtot[w2][lane];
    den_off += dentot[w2];
  }

  u16* op = out2 + (size_t)b * T_ * E_ + h * D_ + lane;
  num = num_off; den = den_off;
  #pragma unroll 8
  for (int j2 = 0; j2 < 64; j2++) {
    const float w = wbuf[j0 + j2];
    num += w * bf2f(rvp[(size_t)(j0 + j2) * ldrv]);
    den += w;
    op[(size_t)(j0 + j2) * E_] = f2bf(num / den);
  }
}

// ---------------------------------------------------------------------------
// transpose_v: qkvr v-view -> blocked vT' [bh][t8][d][t&7]
// ---------------------------------------------------------------------------
__global__ __launch_bounds__(256) void transpose_v(const u16* __restrict__ v, u16* __restrict__ vTb,
                                                   int ldv) {
  const int bh = blockIdx.x;
  const int b = bh >> 4, h = bh & 15;
  const int d0 = blockIdx.y * 32, t0 = blockIdx.z * 32;
  __shared__ u16 tile[32][33];
  const int c = threadIdx.x & 31, r0 = threadIdx.x >> 5;
  #pragma unroll
  for (int rr = 0; rr < 32; rr += 8) {
    const int t = t0 + rr + r0;
    tile[rr + r0][c] = v[((size_t)b * T_ + t) * ldv + h * 64 + d0 + c];
  }
  __syncthreads();
  #pragma unroll
  for (int rr = 0; rr < 32; rr += 8) {
    const int d = d0 + rr + r0;
    const int t = t0 + c;
    vTb[((size_t)(bh * 128 + (t >> 3)) * 64 + d) * 8 + (t & 7)] = tile[c][rr + r0];
  }
}

// ---------------------------------------------------------------------------
extern "C" void kernel_launch(void* const* d_in, const int* in_sizes, int n_in,
                              void* d_out, int out_size, void* d_ws, size_t ws_size,
                              hipStream_t stream) {
  (void)in_sizes; (void)n_in; (void)out_size; (void)ws_size;
  const float* x    = (const float*)d_in[0];
  const float* wq   = (const float*)d_in[1];
  const float* wk   = (const float*)d_in[2];
  const float* wv   = (const float*)d_in[3];
  const float* wvr  = (const float*)d_in[4];
  const float* wr   = (const float*)d_in[5];
  const float* wj   = (const float*)d_in[6];
  const float* gate = (const float*)d_in[7];
  const float* wo   = (const float*)d_in[8];
  float* out = (float*)d_out;

  char* p = (char*)d_ws;
  auto alloc = [&](size_t bytes) -> char* {
    char* r = p; p += (bytes + 255) & ~(size_t)255; return r;
  };
  const size_t NTE = (size_t)B_ * T_ * E_;   // 4M elements
  const size_t NW  = (size_t)E_ * E_;        // 1M elements

  u16* xb    = (u16*)alloc(NTE * 2);
  u16* xlo   = (u16*)alloc(NTE * 2);
  u16* wcat  = (u16*)alloc(4 * NW * 2);
  u16* wjb   = (u16*)alloc(NW * 2);
  u16* wjlo  = (u16*)alloc(NW * 2);
  u16* wob   = (u16*)alloc(NW * 2);
  u16* qkvr  = (u16*)alloc(NTE * 4 * 2);     // (B*T, 4096): q|k|v|rv
  u16* vT    = (u16*)alloc(NTE * 2);         // blocked (bh, t8, d, 8)
  u16* echoT = (u16*)alloc(NTE * 2);         // (B, E, T) bf16
  u16* a3p   = (u16*)alloc(NTE * 2);
  float* sc  = (float*)alloc((size_t)B_ * T_ * 4);
  float* s2  = (float*)alloc((size_t)B_ * H_ * T_ * 4);
  u16* out2b = (u16*)alloc(NTE * 2);
  u16* out3b = (u16*)alloc(NTE * 2);
  u16* comb  = (u16*)alloc(NTE * 2);

  // ---- all casts in one dispatch; sc zeroed for atomic accumulation ----
  cast_all<<<dim3(10240), 256, 0, stream>>>(x, wq, wk, wv, wvr, wo, wj,
                                            xb, xlo, wcat, wob, wjb, wjlo);
  hipMemsetAsync(sc, 0, (size_t)B_ * T_ * 4, stream);

  // ---- fused q|k|v|rv projection: 256^2-tile 8-wave deep pipeline ----
  gemm_qkv8<<<dim3(16, 16), 512, 0, stream>>>(xb, wcat, qkvr);

  // ---- echo split-GEMM: 128x128-tile, 2-phase deep pipeline ----
  gemm_echo8<<<dim3(8, 32), 512, 0, stream>>>(xb, xlo, wjb, wjlo, echoT, sc);

  // ---- side computations ----
  transpose_v<<<dim3(B_ * H_, D_ / 32, T_ / 32), 256, 0, stream>>>(qkvr + 2048, vT, 4096);
  s2_direct<<<dim3(T_ / 32, H_), 256, 0, stream>>>(xb, wr, s2);

  // ---- branch 2 ----
  branch2_scan<<<dim3(H_, B_), 1024, 0, stream>>>(s2, qkvr + 3072, 4096, out2b);

  // ---- branch 3 ----
  a3_softmax<<<dim3(T_, B_), 256, 0, stream>>>(sc, a3p);
  gemm_bt8<true><<<dim3(E_ / 128, T_ / 128, B_), 512, 0, stream>>>(
      a3p, echoT, out3b, T_, T_, T_, E_,
      (long)T_ * T_, (long)E_ * T_, (long)T_ * E_, 1.f);

  // ---- branch 1: flash-fused + vectorized gated-combine epilogue ----
  flash1p2<<<dim3(8, H_, B_), 256, 0, stream>>>(qkvr, vT, out2b, out3b, gate, comb);

  // ---- output projection: deep-pipelined ----
  gemm_bt8<false><<<dim3(E_ / 128, (B_ * T_) / 128, 1), 512, 0, stream>>>(
      comb, wob, out, E_, E_, E_, E_, 0L, 0L, 0L, 1.f);
}

// Round 9
// 328.219 us; speedup vs baseline: 1.0062x; 1.0062x over previous
//
#include <hip/hip_runtime.h>
#include <cstdint>
#include <cstddef>

typedef unsigned short u16;
typedef short bf16x8 __attribute__((ext_vector_type(8)));
typedef short bf16x4 __attribute__((ext_vector_type(4)));
typedef float f32x4 __attribute__((ext_vector_type(4)));

constexpr int B_ = 4, T_ = 1024, E_ = 1024, H_ = 16, D_ = 64;

__device__ __forceinline__ float bf2f(u16 u) {
  union { unsigned u; float f; } v; v.u = ((unsigned)u) << 16; return v.f;
}
__device__ __forceinline__ u16 f2bf(float f) {
  union { float f; unsigned u; } v; v.f = f;
  return (u16)((v.u + 0x7fffu + ((v.u >> 16) & 1u)) >> 16);
}

#define GLD_LDS16(gp, lp)                                                      \
  __builtin_amdgcn_global_load_lds(                                            \
      (const __attribute__((address_space(1))) void*)(gp),                     \
      (__attribute__((address_space(3))) void*)(lp), 16, 0, 0)

#define SBAR()                                                                 \
  do {                                                                         \
    __builtin_amdgcn_sched_barrier(0);                                         \
    __builtin_amdgcn_s_barrier();                                              \
    __builtin_amdgcn_sched_barrier(0);                                         \
  } while (0)
#define WAIT_LGKM0()                                                           \
  do {                                                                         \
    asm volatile("s_waitcnt lgkmcnt(0)" ::: "memory");                         \
    __builtin_amdgcn_sched_barrier(0);                                         \
  } while (0)
#define WAIT_VM4()                                                             \
  do {                                                                         \
    asm volatile("s_waitcnt vmcnt(4)" ::: "memory");                           \
    __builtin_amdgcn_sched_barrier(0);                                         \
  } while (0)
#define WAIT_VM2()                                                             \
  do {                                                                         \
    asm volatile("s_waitcnt vmcnt(2)" ::: "memory");                           \
    __builtin_amdgcn_sched_barrier(0);                                         \
  } while (0)
#define WAIT_VM0()                                                             \
  do {                                                                         \
    asm volatile("s_waitcnt vmcnt(0)" ::: "memory");                           \
    __builtin_amdgcn_sched_barrier(0);                                         \
  } while (0)

// ---------------------------------------------------------------------------
// gemm_qkv8: 256x256-tile 8-wave deep-pipelined bf16 GEMM, C = A @ B^T.
// (round-2 win; ~96% of the K=1024 template ceiling — treated as done.)
// ---------------------------------------------------------------------------
__global__ __launch_bounds__(512, 2) void gemm_qkv8(
    const u16* __restrict__ A, const u16* __restrict__ Bm, u16* __restrict__ C)
{
  __shared__ u16 smem[65536];   // [buf(2)][half(4)][128*64] = 128 KiB

  const int tid  = threadIdx.x;
  const int lane = tid & 63;
  const int wave = tid >> 6;
  const int wm = wave >> 2;      // 0..1  (128-row block)
  const int wn = wave & 3;       // 0..3  (64-col block)
  const int fr = lane & 15;
  const int fg = lane >> 4;
  const int fx = fr & 7;
  const int m0 = blockIdx.y * 256;
  const int n0 = blockIdx.x * 256;

  auto stage = [&](int ktl, int half) {
    const int buf = ktl & 1;                 // logical buffer (pre-clamp!)
    int kt = (ktl > 15) ? 15 : ktl;          // tail: clamped src, benign dest
    const int k0 = kt << 6;
    const u16* src = (half < 2)
        ? (A  + (size_t)(m0 + (half & 1) * 128) * 1024)
        : (Bm + (size_t)(n0 + (half & 1) * 128) * 1024);
    u16* dst = smem + (buf << 15) + (half << 13);
    #pragma unroll
    for (int l = 0; l < 2; l++) {
      const int s = (l << 9) | tid;
      const int r = s >> 3, ch = s & 7;
      GLD_LDS16(src + (size_t)r * 1024 + k0 + ((ch ^ (r & 7)) << 3), dst + s * 8);
    }
  };

  f32x4 acc[8][4];
  #pragma unroll
  for (int i = 0; i < 8; i++)
    #pragma unroll
    for (int j = 0; j < 4; j++) acc[i][j] = f32x4{0.f, 0.f, 0.f, 0.f};

  // ---- prologue: tile0 all halves + tile1 {h2,h0}; wait tile0 landed ----
  stage(0, 0); stage(0, 1); stage(0, 2); stage(0, 3);
  stage(1, 2); stage(1, 0);
  WAIT_VM4();
  __builtin_amdgcn_s_barrier();
  __builtin_amdgcn_sched_barrier(0);

  const int ko0 = (fg ^ fx) << 3;          // ks=0 swizzled chunk offset (elems)
  const int ko1 = ((4 | fg) ^ fx) << 3;    // ks=1

  for (int t = 0; t < 16; t++) {
    const int buf = t & 1;
    const int ab = (buf << 15) + (wm << 13) + fr * 64;
    const int bb = (buf << 15) + 16384 + (wn << 12) + fr * 64;

    bf16x8 aF[4][2], bF[4][2];

    // -------- phase 0 : read aF(mt0-3) + bF(nt0-1); MFMA (lo, np0) --------
    #pragma unroll
    for (int mt = 0; mt < 4; mt++) {
      aF[mt][0] = *(const bf16x8*)(smem + ab + mt * 1024 + ko0);
      aF[mt][1] = *(const bf16x8*)(smem + ab + mt * 1024 + ko1);
    }
    #pragma unroll
    for (int nt = 0; nt < 2; nt++) {
      bF[nt][0] = *(const bf16x8*)(smem + bb + nt * 1024 + ko0);
      bF[nt][1] = *(const bf16x8*)(smem + bb + nt * 1024 + ko1);
    }
    stage(t + 1, 1);
    SBAR();
    WAIT_LGKM0();
    __builtin_amdgcn_s_setprio(1);
    #pragma unroll
    for (int mt = 0; mt < 4; mt++)
      #pragma unroll
      for (int nt = 0; nt < 2; nt++) {
        acc[mt][nt] = __builtin_amdgcn_mfma_f32_16x16x32_bf16(aF[mt][0], bF[nt][0], acc[mt][nt], 0, 0, 0);
        acc[mt][nt] = __builtin_amdgcn_mfma_f32_16x16x32_bf16(aF[mt][1], bF[nt][1], acc[mt][nt], 0, 0, 0);
      }
    __builtin_amdgcn_s_setprio(0);
    SBAR();

    // -------- phase 1 : read bF(nt2-3); MFMA (lo, np1) --------------------
    #pragma unroll
    for (int nt = 2; nt < 4; nt++) {
      bF[nt][0] = *(const bf16x8*)(smem + bb + nt * 1024 + ko0);
      bF[nt][1] = *(const bf16x8*)(smem + bb + nt * 1024 + ko1);
    }
    stage(t + 1, 3);
    SBAR();
    WAIT_LGKM0();
    __builtin_amdgcn_s_setprio(1);
    #pragma unroll
    for (int mt = 0; mt < 4; mt++)
      #pragma unroll
      for (int nt = 2; nt < 4; nt++) {
        acc[mt][nt] = __builtin_amdgcn_mfma_f32_16x16x32_bf16(aF[mt][0], bF[nt][0], acc[mt][nt], 0, 0, 0);
        acc[mt][nt] = __builtin_amdgcn_mfma_f32_16x16x32_bf16(aF[mt][1], bF[nt][1], acc[mt][nt], 0, 0, 0);
      }
    __builtin_amdgcn_s_setprio(0);
    SBAR();

    // -------- phase 2 : read aF(mt4-7, overwrite); MFMA (hi, np0) ---------
    #pragma unroll
    for (int mt = 0; mt < 4; mt++) {
      aF[mt][0] = *(const bf16x8*)(smem + ab + (4 + mt) * 1024 + ko0);
      aF[mt][1] = *(const bf16x8*)(smem + ab + (4 + mt) * 1024 + ko1);
    }
    stage(t + 2, 2);
    SBAR();
    WAIT_LGKM0();
    __builtin_amdgcn_s_setprio(1);
    #pragma unroll
    for (int mt = 0; mt < 4; mt++)
      #pragma unroll
      for (int nt = 0; nt < 2; nt++) {
        acc[4 + mt][nt] = __builtin_amdgcn_mfma_f32_16x16x32_bf16(aF[mt][0], bF[nt][0], acc[4 + mt][nt], 0, 0, 0);
        acc[4 + mt][nt] = __builtin_amdgcn_mfma_f32_16x16x32_bf16(aF[mt][1], bF[nt][1], acc[4 + mt][nt], 0, 0, 0);
      }
    __builtin_amdgcn_s_setprio(0);
    SBAR();

    // -------- phase 3 : MFMA (hi, np1); boundary vmcnt(4) -----------------
    stage(t + 2, 0);
    SBAR();
    __builtin_amdgcn_s_setprio(1);
    #pragma unroll
    for (int mt = 0; mt < 4; mt++)
      #pragma unroll
      for (int nt = 2; nt < 4; nt++) {
        acc[4 + mt][nt] = __builtin_amdgcn_mfma_f32_16x16x32_bf16(aF[mt][0], bF[nt][0], acc[4 + mt][nt], 0, 0, 0);
        acc[4 + mt][nt] = __builtin_amdgcn_mfma_f32_16x16x32_bf16(aF[mt][1], bF[nt][1], acc[4 + mt][nt], 0, 0, 0);
      }
    __builtin_amdgcn_s_setprio(0);
    WAIT_VM4();                             // tile t+1 fully in LDS
    __builtin_amdgcn_s_barrier();
    __builtin_amdgcn_sched_barrier(0);
  }

  // ---- epilogue ----
  u16* Cp = C + (size_t)(m0 + wm * 128) * 4096 + n0 + wn * 64;
  #pragma unroll
  for (int mt = 0; mt < 8; mt++)
    #pragma unroll
    for (int nt = 0; nt < 4; nt++)
      #pragma unroll
      for (int r2 = 0; r2 < 4; r2++)
        Cp[(size_t)(mt * 16 + fg * 4 + r2) * 4096 + nt * 16 + fr] = f2bf(acc[mt][nt][r2]);
}

// ---------------------------------------------------------------------------
// gemm_bt8: batched 128x128-tile 8-wave deep-pipelined bf16 GEMM (round-6 win)
// ---------------------------------------------------------------------------
template<bool CBF16>
__global__ __launch_bounds__(512, 2) void gemm_bt8(
    const u16* __restrict__ A, const u16* __restrict__ Bm, void* __restrict__ Cv,
    int K, int lda, int ldb, int ldc,
    long batchA, long batchB, long batchC, float alpha)
{
  __shared__ u16 smem[32768];   // [buf2][unit2][128*64] = 64 KiB

  const int tid  = threadIdx.x;
  const int lane = tid & 63;
  const int wave = tid >> 6;
  const int wm = wave >> 2;      // 0..1  (64-row block)
  const int wn = wave & 3;       // 0..3  (32-col block)
  const int fr = lane & 15;
  const int fg = lane >> 4;
  const int fx = fr & 7;
  const int m0 = blockIdx.y * 128;
  const int n0 = blockIdx.x * 128;
  const int z  = blockIdx.z;
  const u16* Ab = A  + (size_t)z * batchA;
  const u16* Bb = Bm + (size_t)z * batchB;
  const int NTK = K >> 6;

  auto stage = [&](int ktl, int unit) {
    const int buf = ktl & 1;                 // logical buffer (pre-clamp!)
    int kt = (ktl > NTK - 1) ? NTK - 1 : ktl;
    const int k0 = kt << 6;
    const u16* src = unit ? (Bb + (size_t)n0 * ldb) : (Ab + (size_t)m0 * lda);
    const int ld = unit ? ldb : lda;
    u16* dst = smem + (buf << 14) + (unit << 13);
    #pragma unroll
    for (int l = 0; l < 2; l++) {
      const int s = (l << 9) | tid;
      const int r = s >> 3, ch = s & 7;
      GLD_LDS16(src + (size_t)r * ld + k0 + ((ch ^ (r & 7)) << 3), dst + s * 8);
    }
  };

  f32x4 acc[4][2];
  #pragma unroll
  for (int i = 0; i < 4; i++)
    #pragma unroll
    for (int j = 0; j < 2; j++) acc[i][j] = f32x4{0.f, 0.f, 0.f, 0.f};

  // ---- prologue: tile0 {A,B} + tile1 {A}; wait tile0 landed ----
  stage(0, 0); stage(0, 1); stage(1, 0);
  WAIT_VM2();
  __builtin_amdgcn_s_barrier();
  __builtin_amdgcn_sched_barrier(0);

  const int ko0 = (fg ^ fx) << 3;
  const int ko1 = ((4 | fg) ^ fx) << 3;

  for (int t = 0; t < NTK; t++) {
    const int buf = t & 1;
    const int ab = (buf << 14) + (wm * 64 + fr) * 64;
    const int bb = (buf << 14) + 8192 + (wn * 32 + fr) * 64;

    bf16x8 aF[4][2], bF[2];

    // -------- phase 0 : read all aF + bF(nt0); stage (t+1,B) --------------
    #pragma unroll
    for (int mt = 0; mt < 4; mt++) {
      aF[mt][0] = *(const bf16x8*)(smem + ab + mt * 1024 + ko0);
      aF[mt][1] = *(const bf16x8*)(smem + ab + mt * 1024 + ko1);
    }
    bF[0] = *(const bf16x8*)(smem + bb + ko0);
    bF[1] = *(const bf16x8*)(smem + bb + ko1);
    stage(t + 1, 1);
    SBAR();
    WAIT_LGKM0();
    __builtin_amdgcn_s_setprio(1);
    #pragma unroll
    for (int mt = 0; mt < 4; mt++) {
      acc[mt][0] = __builtin_amdgcn_mfma_f32_16x16x32_bf16(aF[mt][0], bF[0], acc[mt][0], 0, 0, 0);
      acc[mt][0] = __builtin_amdgcn_mfma_f32_16x16x32_bf16(aF[mt][1], bF[1], acc[mt][0], 0, 0, 0);
    }
    __builtin_amdgcn_s_setprio(0);
    SBAR();

    // -------- phase 1 : read bF(nt1); stage (t+2,A); boundary vmcnt(2) ----
    bF[0] = *(const bf16x8*)(smem + bb + 1024 + ko0);
    bF[1] = *(const bf16x8*)(smem + bb + 1024 + ko1);
    stage(t + 2, 0);
    SBAR();
    WAIT_LGKM0();
    __builtin_amdgcn_s_setprio(1);
    #pragma unroll
    for (int mt = 0; mt < 4; mt++) {
      acc[mt][1] = __builtin_amdgcn_mfma_f32_16x16x32_bf16(aF[mt][0], bF[0], acc[mt][1], 0, 0, 0);
      acc[mt][1] = __builtin_amdgcn_mfma_f32_16x16x32_bf16(aF[mt][1], bF[1], acc[mt][1], 0, 0, 0);
    }
    __builtin_amdgcn_s_setprio(0);
    WAIT_VM2();                             // tile t+1 fully in LDS
    __builtin_amdgcn_s_barrier();
    __builtin_amdgcn_sched_barrier(0);
  }

  // ---- epilogue (drain tail stages; then store) ----
  WAIT_VM0();
  #pragma unroll
  for (int mt = 0; mt < 4; mt++) {
    #pragma unroll
    for (int nt = 0; nt < 2; nt++) {
      const int row = m0 + wm * 64 + mt * 16 + fg * 4;
      const int col = n0 + wn * 32 + nt * 16 + fr;
      #pragma unroll
      for (int r2 = 0; r2 < 4; r2++) {
        const float vv = acc[mt][nt][r2] * alpha;
        const size_t ci = (size_t)z * batchC + (size_t)(row + r2) * ldc + col;
        if constexpr (CBF16) ((u16*)Cv)[ci] = f2bf(vv);
        else                 ((float*)Cv)[ci] = vv;
      }
    }
  }
}

// ---------------------------------------------------------------------------
// gemm_echo8: split-bf16 GEMM, 2-phase deep pipeline (round-7 win).
// ---------------------------------------------------------------------------
__global__ __launch_bounds__(512, 2) void gemm_echo8(
    const u16* __restrict__ A, const u16* __restrict__ Alo,
    const u16* __restrict__ Bm, const u16* __restrict__ Blo,
    u16* __restrict__ echoT, float* __restrict__ sc)
{
  __shared__ u16 smem[65536];   // [buf2][unit4][128*64] = 128 KiB

  const int tid  = threadIdx.x;
  const int lane = tid & 63;
  const int wave = tid >> 6;
  const int wm = wave >> 2;      // 0..1  (64-row block)
  const int wn = wave & 3;       // 0..3  (32-col block)
  const int fr = lane & 15;
  const int fg = lane >> 4;
  const int fx = fr & 7;
  const int m0 = blockIdx.y * 128;
  const int n0 = blockIdx.x * 128;

  auto stage = [&](int ktl, int unit) {
    const int buf = ktl & 1;                 // logical buffer (pre-clamp!)
    int kt = (ktl > 15) ? 15 : ktl;          // tail: clamped src, benign dest
    const int k0 = kt << 6;
    const u16* src = (unit == 0) ? A   + (size_t)m0 * 1024
                   : (unit == 1) ? Alo + (size_t)m0 * 1024
                   : (unit == 2) ? Bm  + (size_t)n0 * 1024
                   :               Blo + (size_t)n0 * 1024;
    u16* dst = smem + (buf << 15) + (unit << 13);
    #pragma unroll
    for (int l = 0; l < 2; l++) {
      const int s = (l << 9) | tid;
      const int r = s >> 3, ch = s & 7;
      GLD_LDS16(src + (size_t)r * 1024 + k0 + ((ch ^ (r & 7)) << 3), dst + s * 8);
    }
  };

  f32x4 acc[4][2];
  #pragma unroll
  for (int i = 0; i < 4; i++)
    #pragma unroll
    for (int j = 0; j < 2; j++) acc[i][j] = f32x4{0.f, 0.f, 0.f, 0.f};

  // ---- prologue: tile0 all units + tile1 {Ahi,Alo}; wait tile0 landed ----
  stage(0, 0); stage(0, 1); stage(0, 2); stage(0, 3);
  stage(1, 0); stage(1, 1);
  WAIT_VM4();
  __builtin_amdgcn_s_barrier();
  __builtin_amdgcn_sched_barrier(0);

  const int ko0 = (fg ^ fx) << 3;          // ks=0 swizzled chunk offset (elems)
  const int ko1 = ((4 | fg) ^ fx) << 3;    // ks=1

  for (int t = 0; t < 16; t++) {
    const int buf = t & 1;
    const int ab = (buf << 15) + (wm * 64 + fr) * 64;
    const int bb = (buf << 15) + 16384 + (wn * 32 + fr) * 64;

    bf16x8 aH[4][2], aL[4][2], bH[2], bL[2];

    // -------- phase 0' : read all a-frags + b(nt0, ks0+ks1); MFMA nt0 -----
    #pragma unroll
    for (int mt = 0; mt < 4; mt++) {
      aH[mt][0] = *(const bf16x8*)(smem + ab + mt * 1024 + ko0);
      aH[mt][1] = *(const bf16x8*)(smem + ab + mt * 1024 + ko1);
      aL[mt][0] = *(const bf16x8*)(smem + ab + 8192 + mt * 1024 + ko0);
      aL[mt][1] = *(const bf16x8*)(smem + ab + 8192 + mt * 1024 + ko1);
    }
    bH[0] = *(const bf16x8*)(smem + bb + ko0);
    bL[0] = *(const bf16x8*)(smem + bb + 8192 + ko0);
    bH[1] = *(const bf16x8*)(smem + bb + ko1);
    bL[1] = *(const bf16x8*)(smem + bb + 8192 + ko1);
    stage(t + 1, 2);
    stage(t + 1, 3);
    SBAR();
    WAIT_LGKM0();
    __builtin_amdgcn_s_setprio(1);
    #pragma unroll
    for (int mt = 0; mt < 4; mt++) {
      acc[mt][0] = __builtin_amdgcn_mfma_f32_16x16x32_bf16(aH[mt][0], bH[0], acc[mt][0], 0, 0, 0);
      acc[mt][0] = __builtin_amdgcn_mfma_f32_16x16x32_bf16(aL[mt][0], bH[0], acc[mt][0], 0, 0, 0);
      acc[mt][0] = __builtin_amdgcn_mfma_f32_16x16x32_bf16(aH[mt][0], bL[0], acc[mt][0], 0, 0, 0);
    }
    #pragma unroll
    for (int mt = 0; mt < 4; mt++) {
      acc[mt][0] = __builtin_amdgcn_mfma_f32_16x16x32_bf16(aH[mt][1], bH[1], acc[mt][0], 0, 0, 0);
      acc[mt][0] = __builtin_amdgcn_mfma_f32_16x16x32_bf16(aL[mt][1], bH[1], acc[mt][0], 0, 0, 0);
      acc[mt][0] = __builtin_amdgcn_mfma_f32_16x16x32_bf16(aH[mt][1], bL[1], acc[mt][0], 0, 0, 0);
    }
    __builtin_amdgcn_s_setprio(0);
    SBAR();

    // -------- phase 1' : read b(nt1, ks0+ks1); MFMA nt1; boundary ---------
    bH[0] = *(const bf16x8*)(smem + bb + 1024 + ko0);
    bL[0] = *(const bf16x8*)(smem + bb + 8192 + 1024 + ko0);
    bH[1] = *(const bf16x8*)(smem + bb + 1024 + ko1);
    bL[1] = *(const bf16x8*)(smem + bb + 8192 + 1024 + ko1);
    stage(t + 2, 0);
    stage(t + 2, 1);
    SBAR();
    WAIT_LGKM0();
    __builtin_amdgcn_s_setprio(1);
    #pragma unroll
    for (int mt = 0; mt < 4; mt++) {
      acc[mt][1] = __builtin_amdgcn_mfma_f32_16x16x32_bf16(aH[mt][0], bH[0], acc[mt][1], 0, 0, 0);
      acc[mt][1] = __builtin_amdgcn_mfma_f32_16x16x32_bf16(aL[mt][0], bH[0], acc[mt][1], 0, 0, 0);
      acc[mt][1] = __builtin_amdgcn_mfma_f32_16x16x32_bf16(aH[mt][0], bL[0], acc[mt][1], 0, 0, 0);
    }
    #pragma unroll
    for (int mt = 0; mt < 4; mt++) {
      acc[mt][1] = __builtin_amdgcn_mfma_f32_16x16x32_bf16(aH[mt][1], bH[1], acc[mt][1], 0, 0, 0);
      acc[mt][1] = __builtin_amdgcn_mfma_f32_16x16x32_bf16(aL[mt][1], bH[1], acc[mt][1], 0, 0, 0);
      acc[mt][1] = __builtin_amdgcn_mfma_f32_16x16x32_bf16(aH[mt][1], bL[1], acc[mt][1], 0, 0, 0);
    }
    __builtin_amdgcn_s_setprio(0);
    WAIT_VM4();                             // tile t+1 fully in LDS
    __builtin_amdgcn_s_barrier();
    __builtin_amdgcn_sched_barrier(0);
  }

  // ---- fused epilogue (drain tail stages before reusing smem) ----
  asm volatile("s_waitcnt vmcnt(0) lgkmcnt(0)" ::: "memory");
  __builtin_amdgcn_sched_barrier(0);
  __builtin_amdgcn_s_barrier();
  __builtin_amdgcn_sched_barrier(0);

  const int b   = m0 >> 10;
  const int t0l = m0 & 1023;
  u16* lt = smem;                  // [f(128)][t(128)] tile, pad 132

  #pragma unroll
  for (int mt = 0; mt < 4; mt++) {
    float sq[4] = {0.f, 0.f, 0.f, 0.f};
    #pragma unroll
    for (int nt = 0; nt < 2; nt++) {
      const int cl = wn * 32 + nt * 16 + fr;
      #pragma unroll
      for (int r2 = 0; r2 < 4; r2++) {
        const float vv = acc[mt][nt][r2];
        sq[r2] += vv * vv;
        lt[cl * 132 + wm * 64 + mt * 16 + fg * 4 + r2] = f2bf(vv);
      }
    }
    #pragma unroll
    for (int m2 = 1; m2 < 16; m2 <<= 1) {
      sq[0] += __shfl_xor(sq[0], m2, 64);
      sq[1] += __shfl_xor(sq[1], m2, 64);
      sq[2] += __shfl_xor(sq[2], m2, 64);
      sq[3] += __shfl_xor(sq[3], m2, 64);
    }
    if (fr == 0) {
      #pragma unroll
      for (int r2 = 0; r2 < 4; r2++)
        atomicAdd(&sc[(size_t)b * T_ + t0l + wm * 64 + mt * 16 + fg * 4 + r2], sq[r2]);
    }
  }
  __syncthreads();
  for (int s = tid; s < 128 * 128; s += 512) {
    const int f = s >> 7, tt = s & 127;
    echoT[((size_t)b * E_ + n0 + f) * T_ + t0l + tt] = lt[f * 132 + tt];
  }
}

// ---------------------------------------------------------------------------
// flash1q: flash-fused branch 1 + gated combine.  Round-9: PAIR-FUSED K/V —
// both q-tiles (itA=x small, itB=15-x large, nA<=nB) are processed per K/V
// step, so each K/V tile is staged ONCE per pair: stagings 72->52 per (h,b)
// (-28% K/V fetch), barriers 72->52, and aK/bV LDS fragments are loaded once
// and consumed by both tiles' MFMAs (~half the LDS reads).  Per-block MFMA
// work is uniform (nA+nB=9 for all x).  Per-tile accumulation order, masks,
// rounding identical -> bit-exact.  LDS 80KB (2 blocks/CU), lb(256,2).
// ---------------------------------------------------------------------------
__global__ __launch_bounds__(256, 2) void flash1q(
    const u16* __restrict__ qkvr, const u16* __restrict__ vTb,
    const u16* __restrict__ out2, const u16* __restrict__ out3,
    const float* __restrict__ gate, u16* __restrict__ comb) {
  const int x = blockIdx.x, h = blockIdx.y, b = blockIdx.z;
  const int tid = threadIdx.x, lane = tid & 63, w = tid >> 6;
  const int fr = lane & 15, fg = lane >> 4;
  const int itA = x, itB = 15 - x;               // 64-row q-tiles
  const int nA = (itA >> 1) + 1, nB = (itB >> 1) + 1;   // nA <= nB

  __shared__ u16 sQ[2][4096];          // [tile][64x64]
  __shared__ u16 sK[2][8192];          // 128x64, double-buffered
  __shared__ u16 sV[2][8192];

  const u16* Kb = qkvr + (size_t)(b * T_) * 4096 + 1024 + h * 64;
  const u16* Vb = vTb + (size_t)(b * H_ + h) * (D_ * T_);

  // gate coefficients (exactly as combine_gate computed them)
  const float g0 = gate[h * 3 + 0], g1 = gate[h * 3 + 1], g2 = gate[h * 3 + 2];
  const float gmx = fmaxf(g0, fmaxf(g1, g2));
  const float e0 = __expf(g0 - gmx), e1 = __expf(g1 - gmx), e2 = __expf(g2 - gmx);
  const float ginv = 1.0f / (e0 + e1 + e2);

  auto stageQ = [&](int it, int qb) {
    const u16* Qb = qkvr + ((size_t)(b * T_) + it * 64) * 4096 + h * 64;
    #pragma unroll
    for (int s0 = 0; s0 < 512; s0 += 256) {
      const int s = s0 + tid;
      const int l = s & 63, g = s >> 6;
      const int row = (g >> 1) * 16 + (l & 15);
      const int c8  = (g & 1) * 4 + (l >> 4);
      GLD_LDS16(Qb + (size_t)row * 4096 + c8 * 8, &sQ[qb][s * 8]);
    }
  };
  auto stageKV = [&](int jt, int bi) {
    #pragma unroll
    for (int s0 = 0; s0 < 1024; s0 += 256) {
      const int s = s0 + tid;
      const int l = s & 63, g = s >> 6;
      const int row = (g >> 1) * 16 + (l & 15);
      const int c8  = (g & 1) * 4 + (l >> 4);
      GLD_LDS16(Kb + (size_t)(jt * 128 + row) * 4096 + c8 * 8, &sK[bi][s * 8]);
    }
    #pragma unroll
    for (int s0 = 0; s0 < 1024; s0 += 256) {
      const int s = s0 + tid;
      const int jc = s >> 6, d = s & 63;
      GLD_LDS16(Vb + ((size_t)(jt * 16 + jc)) * 512 + d * 8, &sV[bi][s * 8]);
    }
  };

  // online-softmax step for one tile (identical op sequence to flash1p2)
  auto sm_step = [&](f32x4 (&st)[8], int it, int kbase, bool diag,
                     float& mrow, float& lrow, f32x4 (&accO)[4], bf16x4 (&pf)[8]) {
    const int iloc = it * 64 + w * 16 + fr;
    float sv[8][4];
    float rmax = -3.0e38f;
    #pragma unroll
    for (int nf = 0; nf < 8; nf++)
      #pragma unroll
      for (int r = 0; r < 4; r++) {
        float s = st[nf][r] * 0.125f;
        if (diag && (kbase + nf * 16 + fg * 4 + r) > iloc) s = -3.0e38f;
        sv[nf][r] = s;
        rmax = fmaxf(rmax, s);
      }
    rmax = fmaxf(rmax, __shfl_xor(rmax, 16, 64));
    rmax = fmaxf(rmax, __shfl_xor(rmax, 32, 64));
    const float mn = fmaxf(mrow, rmax);
    const float al = __expf(mrow - mn);
    mrow = mn;
    float ps = 0.f;
    #pragma unroll
    for (int nf = 0; nf < 8; nf++)
      #pragma unroll
      for (int r = 0; r < 4; r++) {
        const float pv = __expf(sv[nf][r] - mn);
        ps += pv;
        pf[nf][r] = (short)f2bf(pv);
      }
    ps += __shfl_xor(ps, 16, 64);
    ps += __shfl_xor(ps, 32, 64);
    lrow = lrow * al + ps;
    #pragma unroll
    for (int r = 0; r < 4; r++) {
      const float alr = __shfl(al, fg * 4 + r, 64);
      #pragma unroll
      for (int nd = 0; nd < 4; nd++) accO[nd][r] *= alr;
    }
  };

  // ---- prologue: Q(A), Q(B) + K/V(0) -> buf0 ----
  stageQ(itA, 0);
  stageQ(itB, 1);
  stageKV(0, 0);
  asm volatile("s_waitcnt vmcnt(0)" ::: "memory");
  __syncthreads();

  bf16x8 bQA[2], bQB[2];
  #pragma unroll
  for (int kk = 0; kk < 2; kk++) {
    bQA[kk] = *(const bf16x8*)&sQ[0][(((w * 2 + kk) << 6) | lane) * 8];
    bQB[kk] = *(const bf16x8*)&sQ[1][(((w * 2 + kk) << 6) | lane) * 8];
  }

  f32x4 accOA[4], accOB[4];
  float mA = -3.0e38f, lA = 0.f, mB = -3.0e38f, lB = 0.f;
  #pragma unroll
  for (int nd = 0; nd < 4; nd++) {
    accOA[nd] = f32x4{0.f, 0.f, 0.f, 0.f};
    accOB[nd] = f32x4{0.f, 0.f, 0.f, 0.f};
  }

  for (int jt = 0; jt < nB; jt++) {
    const int bi = jt & 1;
    if (jt < nB - 1) stageKV(jt + 1, bi ^ 1);
    const bool actA = (jt < nA);

    // ---- QK^T: shared aK, one or two MFMAs per fragment ----
    f32x4 stA[8], stB[8];
    #pragma unroll
    for (int nf = 0; nf < 8; nf++) {
      stA[nf] = f32x4{0.f, 0.f, 0.f, 0.f};
      stB[nf] = f32x4{0.f, 0.f, 0.f, 0.f};
    }
    if (actA) {
      #pragma unroll
      for (int kk = 0; kk < 2; kk++)
        #pragma unroll
        for (int nf = 0; nf < 8; nf++) {
          const bf16x8 aK = *(const bf16x8*)&sK[bi][((((nf << 1) | kk) << 6) | lane) * 8];
          stB[nf] = __builtin_amdgcn_mfma_f32_16x16x32_bf16(aK, bQB[kk], stB[nf], 0, 0, 0);
          stA[nf] = __builtin_amdgcn_mfma_f32_16x16x32_bf16(aK, bQA[kk], stA[nf], 0, 0, 0);
        }
    } else {
      #pragma unroll
      for (int kk = 0; kk < 2; kk++)
        #pragma unroll
        for (int nf = 0; nf < 8; nf++) {
          const bf16x8 aK = *(const bf16x8*)&sK[bi][((((nf << 1) | kk) << 6) | lane) * 8];
          stB[nf] = __builtin_amdgcn_mfma_f32_16x16x32_bf16(aK, bQB[kk], stB[nf], 0, 0, 0);
        }
    }

    // ---- online softmax per tile ----
    bf16x4 pfA[8], pfB[8];
    sm_step(stB, itB, jt * 128, jt == nB - 1, mB, lB, accOB, pfB);
    if (actA) sm_step(stA, itA, jt * 128, jt == nA - 1, mA, lA, accOA, pfA);

    // ---- PV: shared bV ----
    if (actA) {
      #pragma unroll
      for (int kc = 0; kc < 8; kc++) {
        bf16x8 bV[4];
        #pragma unroll
        for (int nd = 0; nd < 4; nd++) {
          const bf16x4 vv = *(const bf16x4*)&sV[bi][
              (((kc * 2 + (fg >> 1)) * 64 + nd * 16 + fr) * 8) + (fg & 1) * 4];
          bV[nd] = bf16x8{vv[0], vv[1], vv[2], vv[3], 0, 0, 0, 0};
        }
        const bf16x4 pb = pfB[kc];
        const bf16x8 pB = bf16x8{pb[0], pb[1], pb[2], pb[3], 0, 0, 0, 0};
        const bf16x4 pa = pfA[kc];
        const bf16x8 pA = bf16x8{pa[0], pa[1], pa[2], pa[3], 0, 0, 0, 0};
        #pragma unroll
        for (int nd = 0; nd < 4; nd++) {
          accOB[nd] = __builtin_amdgcn_mfma_f32_16x16x32_bf16(pB, bV[nd], accOB[nd], 0, 0, 0);
          accOA[nd] = __builtin_amdgcn_mfma_f32_16x16x32_bf16(pA, bV[nd], accOA[nd], 0, 0, 0);
        }
      }
    } else {
      #pragma unroll
      for (int kc = 0; kc < 8; kc++) {
        bf16x8 bV[4];
        #pragma unroll
        for (int nd = 0; nd < 4; nd++) {
          const bf16x4 vv = *(const bf16x4*)&sV[bi][
              (((kc * 2 + (fg >> 1)) * 64 + nd * 16 + fr) * 8) + (fg & 1) * 4];
          bV[nd] = bf16x8{vv[0], vv[1], vv[2], vv[3], 0, 0, 0, 0};
        }
        const bf16x4 pb = pfB[kc];
        const bf16x8 pB = bf16x8{pb[0], pb[1], pb[2], pb[3], 0, 0, 0, 0};
        #pragma unroll
        for (int nd = 0; nd < 4; nd++)
          accOB[nd] = __builtin_amdgcn_mfma_f32_16x16x32_bf16(pB, bV[nd], accOB[nd], 0, 0, 0);
      }
    }

    // ---- late wait: prefetch landed + everyone done with buffers ----
    asm volatile("s_waitcnt vmcnt(0)" ::: "memory");
    __syncthreads();
  }

  // ---- epilogue: both tiles through dead sK, vectorized gated combine ----
  u16* ltA = &sK[0][0];                 // [64][72] o1 tiles (4608 u16 each)
  u16* ltB = &sK[1][0];
  const float liA = 1.0f / lA;
  const float liB = 1.0f / lB;
  #pragma unroll
  for (int r = 0; r < 4; r++) {
    const float lvA = __shfl(liA, fg * 4 + r, 64);
    const float lvB = __shfl(liB, fg * 4 + r, 64);
    const int row = w * 16 + fg * 4 + r;
    #pragma unroll
    for (int nd = 0; nd < 4; nd++) {
      ltA[row * 72 + nd * 16 + fr] = f2bf(accOA[nd][r] * lvA);
      ltB[row * 72 + nd * 16 + fr] = f2bf(accOB[nd][r] * lvB);
    }
  }
  __syncthreads();
  #pragma unroll
  for (int s0 = 0; s0 < 1024; s0 += 256) {
    const int s = s0 + tid;
    const int tile = s >> 9;
    const int sr = s & 511;
    const int row = sr >> 3, c8 = (sr & 7) * 8;
    const int it = tile ? itB : itA;
    const u16* lt = tile ? ltB : ltA;
    const size_t gidx = ((size_t)(b * T_) + it * 64 + row) * E_ + h * 64 + c8;
    const bf16x8 o1v = *(const bf16x8*)&lt[row * 72 + c8];
    const bf16x8 o2v = *(const bf16x8*)&out2[gidx];
    const bf16x8 o3v = *(const bf16x8*)&out3[gidx];
    bf16x8 ov;
    #pragma unroll
    for (int e = 0; e < 8; e++) {
      const float o = (e0 * bf2f((u16)o1v[e]) + e1 * bf2f((u16)o2v[e])
                     + e2 * bf2f((u16)o3v[e])) * ginv;
      ov[e] = (short)f2bf(o);
    }
    *(bf16x8*)&comb[gidx] = ov;
  }
}

// ---------------------------------------------------------------------------
// Reductions
// ---------------------------------------------------------------------------
__device__ __forceinline__ float block_max256(float v, float* red) {
  #pragma unroll
  for (int m = 32; m > 0; m >>= 1) v = fmaxf(v, __shfl_xor(v, m, 64));
  if ((threadIdx.x & 63) == 0) red[threadIdx.x >> 6] = v;
  __syncthreads();
  const float r = fmaxf(fmaxf(red[0], red[1]), fmaxf(red[2], red[3]));
  __syncthreads();
  return r;
}
__device__ __forceinline__ float block_sum256(float v, float* red) {
  #pragma unroll
  for (int m = 32; m > 0; m >>= 1) v += __shfl_xor(v, m, 64);
  if ((threadIdx.x & 63) == 0) red[threadIdx.x >> 6] = v;
  __syncthreads();
  const float r = (red[0] + red[1]) + (red[2] + red[3]);
  __syncthreads();
  return r;
}

// ---------------------------------------------------------------------------
// cast_all: x split (4096 blocks) | wq/wk/wv/wvr -> wcat (4096) |
//           wo -> wob (1024) | wj split (1024).  One dispatch, 10240 blocks.
// ---------------------------------------------------------------------------
__global__ __launch_bounds__(256) void cast_all(
    const float* __restrict__ x, const float* __restrict__ wq,
    const float* __restrict__ wk, const float* __restrict__ wv,
    const float* __restrict__ wvr, const float* __restrict__ wo,
    const float* __restrict__ wj,
    u16* __restrict__ xb, u16* __restrict__ xlo, u16* __restrict__ wcat,
    u16* __restrict__ wob, u16* __restrict__ wjb, u16* __restrict__ wjlo) {
  const int bid = blockIdx.x;
  if (bid < 4096) {
    const size_t i = ((size_t)bid * 256 + threadIdx.x) * 4;
    const float4 v = *(const float4*)(x + i);
    ushort4 oh, ol;
    oh.x = f2bf(v.x); ol.x = f2bf(v.x - bf2f(oh.x));
    oh.y = f2bf(v.y); ol.y = f2bf(v.y - bf2f(oh.y));
    oh.z = f2bf(v.z); ol.z = f2bf(v.z - bf2f(oh.z));
    oh.w = f2bf(v.w); ol.w = f2bf(v.w - bf2f(oh.w));
    *(ushort4*)(xb + i) = oh;
    *(ushort4*)(xlo + i) = ol;
  } else if (bid < 8192) {
    const int r = (bid - 4096) >> 10;
    const float* src = (r == 0) ? wq : (r == 1) ? wk : (r == 2) ? wv : wvr;
    const size_t i = ((size_t)((bid - 4096) & 1023) * 256 + threadIdx.x) * 4;
    const float4 v = *(const float4*)(src + i);
    ushort4 o;
    o.x = f2bf(v.x); o.y = f2bf(v.y); o.z = f2bf(v.z); o.w = f2bf(v.w);
    *(ushort4*)(wcat + (size_t)r * (1 << 20) + i) = o;
  } else if (bid < 9216) {
    const size_t i = ((size_t)(bid - 8192) * 256 + threadIdx.x) * 4;
    const float4 v = *(const float4*)(wo + i);
    ushort4 o;
    o.x = f2bf(v.x); o.y = f2bf(v.y); o.z = f2bf(v.z); o.w = f2bf(v.w);
    *(ushort4*)(wob + i) = o;
  } else {
    const size_t i = ((size_t)(bid - 9216) * 256 + threadIdx.x) * 4;
    const float4 v = *(const float4*)(wj + i);
    ushort4 oh, ol;
    oh.x = f2bf(v.x); ol.x = f2bf(v.x - bf2f(oh.x));
    oh.y = f2bf(v.y); ol.y = f2bf(v.y - bf2f(oh.y));
    oh.z = f2bf(v.z); ol.z = f2bf(v.z - bf2f(oh.z));
    oh.w = f2bf(v.w); ol.w = f2bf(v.w - bf2f(oh.w));
    *(ushort4*)(wjb + i) = oh;
    *(ushort4*)(wjlo + i) = ol;
  }
}

// ---------------------------------------------------------------------------
// s2_direct: s2[b,h,t] = dot(x[b,t,:], wr[h,:,t]) / 8 without materializing
// wrT. Grid (T/32, H).
// ---------------------------------------------------------------------------
__global__ __launch_bounds__(256) void s2_direct(
    const u16* __restrict__ xb, const float* __restrict__ wr, float* __restrict__ s2) {
  const int t0 = blockIdx.x * 32, h = blockIdx.y;
  const int tt = threadIdx.x & 31, eg = threadIdx.x >> 5;
  float acc[4] = {0.f, 0.f, 0.f, 0.f};
  const float* wp = wr + (size_t)h * E_ * T_ + t0 + tt;
  for (int ec = 0; ec < 8; ec++) {
    const int e0 = ec * 128 + eg * 16;
    bf16x8 xv[4][2];
    #pragma unroll
    for (int b = 0; b < 4; b++) {
      const u16* xp = xb + ((size_t)(b * T_) + t0 + tt) * E_ + e0;
      xv[b][0] = *(const bf16x8*)xp;
      xv[b][1] = *(const bf16x8*)(xp + 8);
    }
    #pragma unroll
    for (int e2 = 0; e2 < 16; e2++) {
      const float w = wp[(size_t)(e0 + e2) * T_];
      #pragma unroll
      for (int b = 0; b < 4; b++)
        acc[b] += bf2f((u16)xv[b][e2 >> 3][e2 & 7]) * w;
    }
  }
  __shared__ float red[8][4][33];
  #pragma unroll
  for (int b = 0; b < 4; b++) red[eg][b][tt] = acc[b];
  __syncthreads();
  if (threadIdx.x < 128) {
    const int b = threadIdx.x >> 5, t = threadIdx.x & 31;
    float s = 0.f;
    #pragma unroll
    for (int g = 0; g < 8; g++) s += red[g][b][t];
    s2[((size_t)b * H_ + h) * T_ + t0 + t] = s * 0.125f;
  }
}

// ---------------------------------------------------------------------------
// a3[b,i,j] = softmax_{j<=i}(sc_i*sc_j/1024)  (sc holds raw sum of squares)
// ---------------------------------------------------------------------------
__global__ __launch_bounds__(256) void a3_softmax(const float* __restrict__ sc, u16* __restrict__ a3) {
  const int i = blockIdx.x;
  const int b = blockIdx.y;
  const float* sr = sc + (size_t)b * T_;
  const float sci = sr[i] * 0.03125f;
  u16* row = a3 + ((size_t)b * T_ + i) * T_;
  __shared__ float red[4];
  float v[4];
  float m = -3.0e38f;
  #pragma unroll
  for (int k = 0; k < 4; k++) {
    const int j = threadIdx.x + k * 256;
    const float xv = (j <= i) ? sci * (sr[j] * 0.03125f) : -3.0e38f;
    v[k] = xv;
    m = fmaxf(m, xv);
  }
  m = block_max256(m, red);
  float s = 0.f;
  #pragma unroll
  for (int k = 0; k < 4; k++) {
    const int j = threadIdx.x + k * 256;
    const float p = (j <= i) ? __expf(v[k] - m) : 0.f;
    v[k] = p;
    s += p;
  }
  s = block_sum256(s, red);
  const float inv = 1.0f / s;
  #pragma unroll
  for (int k = 0; k < 4; k++) {
    const int j = threadIdx.x + k * 256;
    row[j] = f2bf(v[k] * inv);
  }
}

// ---------------------------------------------------------------------------
// Branch 2: prefix scan (round-1 win). rv strided view into qkvr.
// ---------------------------------------------------------------------------
__global__ __launch_bounds__(1024) void branch2_scan(
    const float* __restrict__ s2, const u16* __restrict__ rv, int ldrv,
    u16* __restrict__ out2) {
  const int h = blockIdx.x, b = blockIdx.y;
  const int tid = threadIdx.x;
  const int lane = tid & 63;
  const int wv = tid >> 6;

  const float* srow = s2 + ((size_t)b * H_ + h) * T_;

  __shared__ float wbuf[T_];
  __shared__ float numtot[16][64];
  __shared__ float dentot[16];
  __shared__ float redm[16];

  float m = srow[tid];
  #pragma unroll
  for (int mk = 32; mk > 0; mk >>= 1) m = fmaxf(m, __shfl_xor(m, mk, 64));
  if (lane == 0) redm[wv] = m;
  __syncthreads();
  m = redm[0];
  #pragma unroll
  for (int i2 = 1; i2 < 16; i2++) m = fmaxf(m, redm[i2]);

  wbuf[tid] = __expf(srow[tid] - m);
  __syncthreads();

  const u16* rvp = rv + (size_t)(b * T_) * ldrv + h * D_ + lane;
  const int j0 = wv * 64;
  float num = 0.f, den = 0.f;
  #pragma unroll 8
  for (int j2 = 0; j2 < 64; j2++) {
    const float w = wbuf[j0 + j2];
    den += w;
    num += w * bf2f(rvp[(size_t)(j0 + j2) * ldrv]);
  }
  numtot[wv][lane] = num;
  if (lane == 0) dentot[wv] = den;
  __syncthreads();

  float num_off = 0.f, den_off = 0.f;
  for (int w2 = 0; w2 < wv; w2++) {
    num_off += numtot[w2][lane];
    den_off += dentot[w2];
  }

  u16* op = out2 + (size_t)b * T_ * E_ + h * D_ + lane;
  num = num_off; den = den_off;
  #pragma unroll 8
  for (int j2 = 0; j2 < 64; j2++) {
    const float w = wbuf[j0 + j2];
    num += w * bf2f(rvp[(size_t)(j0 + j2) * ldrv]);
    den += w;
    op[(size_t)(j0 + j2) * E_] = f2bf(num / den);
  }
}

// ---------------------------------------------------------------------------
// transpose_v: qkvr v-view -> blocked vT' [bh][t8][d][t&7]
// ---------------------------------------------------------------------------
__global__ __launch_bounds__(256) void transpose_v(const u16* __restrict__ v, u16* __restrict__ vTb,
                                                   int ldv) {
  const int bh = blockIdx.x;
  const int b = bh >> 4, h = bh & 15;
  const int d0 = blockIdx.y * 32, t0 = blockIdx.z * 32;
  __shared__ u16 tile[32][33];
  const int c = threadIdx.x & 31, r0 = threadIdx.x >> 5;
  #pragma unroll
  for (int rr = 0; rr < 32; rr += 8) {
    const int t = t0 + rr + r0;
    tile[rr + r0][c] = v[((size_t)b * T_ + t) * ldv + h * 64 + d0 + c];
  }
  __syncthreads();
  #pragma unroll
  for (int rr = 0; rr < 32; rr += 8) {
    const int d = d0 + rr + r0;
    const int t = t0 + c;
    vTb[((size_t)(bh * 128 + (t >> 3)) * 64 + d) * 8 + (t & 7)] = tile[c][rr + r0];
  }
}

// ---------------------------------------------------------------------------
extern "C" void kernel_launch(void* const* d_in, const int* in_sizes, int n_in,
                              void* d_out, int out_size, void* d_ws, size_t ws_size,
                              hipStream_t stream) {
  (void)in_sizes; (void)n_in; (void)out_size; (void)ws_size;
  const float* x    = (const float*)d_in[0];
  const float* wq   = (const float*)d_in[1];
  const float* wk   = (const float*)d_in[2];
  const float* wv   = (const float*)d_in[3];
  const float* wvr  = (const float*)d_in[4];
  const float* wr   = (const float*)d_in[5];
  const float* wj   = (const float*)d_in[6];
  const float* gate = (const float*)d_in[7];
  const float* wo   = (const float*)d_in[8];
  float* out = (float*)d_out;

  char* p = (char*)d_ws;
  auto alloc = [&](size_t bytes) -> char* {
    char* r = p; p += (bytes + 255) & ~(size_t)255; return r;
  };
  const size_t NTE = (size_t)B_ * T_ * E_;   // 4M elements
  const size_t NW  = (size_t)E_ * E_;        // 1M elements

  u16* xb    = (u16*)alloc(NTE * 2);
  u16* xlo   = (u16*)alloc(NTE * 2);
  u16* wcat  = (u16*)alloc(4 * NW * 2);
  u16* wjb   = (u16*)alloc(NW * 2);
  u16* wjlo  = (u16*)alloc(NW * 2);
  u16* wob   = (u16*)alloc(NW * 2);
  u16* qkvr  = (u16*)alloc(NTE * 4 * 2);     // (B*T, 4096): q|k|v|rv
  u16* vT    = (u16*)alloc(NTE * 2);         // blocked (bh, t8, d, 8)
  u16* echoT = (u16*)alloc(NTE * 2);         // (B, E, T) bf16
  u16* a3p   = (u16*)alloc(NTE * 2);
  float* sc  = (float*)alloc((size_t)B_ * T_ * 4);
  float* s2  = (float*)alloc((size_t)B_ * H_ * T_ * 4);
  u16* out2b = (u16*)alloc(NTE * 2);
  u16* out3b = (u16*)alloc(NTE * 2);
  u16* comb  = (u16*)alloc(NTE * 2);

  // ---- all casts in one dispatch; sc zeroed for atomic accumulation ----
  cast_all<<<dim3(10240), 256, 0, stream>>>(x, wq, wk, wv, wvr, wo, wj,
                                            xb, xlo, wcat, wob, wjb, wjlo);
  hipMemsetAsync(sc, 0, (size_t)B_ * T_ * 4, stream);

  // ---- fused q|k|v|rv projection: 256^2-tile 8-wave deep pipeline ----
  gemm_qkv8<<<dim3(16, 16), 512, 0, stream>>>(xb, wcat, qkvr);

  // ---- echo split-GEMM: 128x128-tile, 2-phase deep pipeline ----
  gemm_echo8<<<dim3(8, 32), 512, 0, stream>>>(xb, xlo, wjb, wjlo, echoT, sc);

  // ---- side computations ----
  transpose_v<<<dim3(B_ * H_, D_ / 32, T_ / 32), 256, 0, stream>>>(qkvr + 2048, vT, 4096);
  s2_direct<<<dim3(T_ / 32, H_), 256, 0, stream>>>(xb, wr, s2);

  // ---- branch 2 ----
  branch2_scan<<<dim3(H_, B_), 1024, 0, stream>>>(s2, qkvr + 3072, 4096, out2b);

  // ---- branch 3 ----
  a3_softmax<<<dim3(T_, B_), 256, 0, stream>>>(sc, a3p);
  gemm_bt8<true><<<dim3(E_ / 128, T_ / 128, B_), 512, 0, stream>>>(
      a3p, echoT, out3b, T_, T_, T_, E_,
      (long)T_ * T_, (long)E_ * T_, (long)T_ * E_, 1.f);

  // ---- branch 1: pair-fused flash + vectorized gated-combine epilogue ----
  flash1q<<<dim3(8, H_, B_), 256, 0, stream>>>(qkvr, vT, out2b, out3b, gate, comb);

  // ---- output projection: deep-pipelined ----
  gemm_bt8<false><<<dim3(E_ / 128, (B_ * T_) / 128, 1), 512, 0, stream>>>(
      comb, wob, out, E_, E_, E_, E_, 0L, 0L, 0L, 1.f);
}